// Round 1
// baseline (13276.628 us; speedup 1.0000x reference)
//
#include <hip/hip_runtime.h>
#include <hip/hip_bf16.h>
#include <math.h>

#define HIDDIM 64
#define EDIM 16

// ---------------------------------------------------------------------------
// Generic 64x64 GEMM: out[row][j] = act( sum_k in[row][k]*W[k][j] + b[j] )
// lane = row; j fully unrolled into 64 accumulators; W/b reads are
// wave-uniform -> scalar loads through sK$.
// ---------------------------------------------------------------------------
__global__ __launch_bounds__(256) void gemm64_kernel(
    const float* __restrict__ in, const float* __restrict__ W,
    const float* __restrict__ b, float* __restrict__ out, int n, int relu)
{
    int row = blockIdx.x * 256 + threadIdx.x;
    if (row >= n) return;
    float acc[64];
#pragma unroll
    for (int j = 0; j < 64; ++j) acc[j] = b[j];
    const float4* in4 = reinterpret_cast<const float4*>(in + (size_t)row * 64);
#pragma unroll 1
    for (int kc = 0; kc < 16; ++kc) {
        float4 x = in4[kc];
        float xs[4] = {x.x, x.y, x.z, x.w};
        const float* Wr = W + kc * 4 * 64;
#pragma unroll
        for (int kk = 0; kk < 4; ++kk) {
            float xv = xs[kk];
            const float* Wk = Wr + kk * 64;
#pragma unroll
            for (int j = 0; j < 64; ++j) acc[j] += xv * Wk[j];
        }
    }
    float* o = out + (size_t)row * 64;
#pragma unroll
    for (int j = 0; j < 64; ++j) {
        float v = acc[j];
        if (relu) v = v > 0.f ? v : 0.f;
        o[j] = v;
    }
}

// ---------------------------------------------------------------------------
// Message kernel: per edge e:
//   cat = [h[src], h[dst], ef]  (144)
//   t = relu(cat @ W1 + b1)     (64)
//   m = t @ W2 + b2             (64)
//   atomicAdd agg[dst] += m
// lane = edge. t round-trips through wave-private LDS (row-contiguous both
// ways -> conflict free; intra-wave ordering via lgkmcnt(0)).
// ---------------------------------------------------------------------------
__global__ __launch_bounds__(256) void msg_kernel(
    const float* __restrict__ h, const int* __restrict__ src,
    const int* __restrict__ dst, const float* __restrict__ ef,
    const float* __restrict__ W1, const float* __restrict__ b1,
    const float* __restrict__ W2, const float* __restrict__ b2,
    float* __restrict__ agg, int nE)
{
    __shared__ float t_lds[4][64][64];  // 64 KB, per-wave slices
    int e = blockIdx.x * 256 + threadIdx.x;
    int w = threadIdx.x >> 6;
    int lane = threadIdx.x & 63;
    bool active = e < nE;
    int ec = active ? e : 0;
    int s = src[ec];
    int d = dst[ec];

    float acc[64];
#pragma unroll
    for (int j = 0; j < 64; ++j) acc[j] = b1[j];

    // ---- stage 1: k = 0..63 (h[src]) ----
    const float4* hs4 = reinterpret_cast<const float4*>(h + (size_t)s * 64);
#pragma unroll 1
    for (int kc = 0; kc < 16; ++kc) {
        float4 x = hs4[kc];
        float xs[4] = {x.x, x.y, x.z, x.w};
        const float* Wr = W1 + kc * 4 * 64;
#pragma unroll
        for (int kk = 0; kk < 4; ++kk) {
            float xv = xs[kk];
            const float* Wk = Wr + kk * 64;
#pragma unroll
            for (int j = 0; j < 64; ++j) acc[j] += xv * Wk[j];
        }
    }
    // ---- stage 1: k = 64..127 (h[dst]) ----
    const float4* hd4 = reinterpret_cast<const float4*>(h + (size_t)d * 64);
#pragma unroll 1
    for (int kc = 0; kc < 16; ++kc) {
        float4 x = hd4[kc];
        float xs[4] = {x.x, x.y, x.z, x.w};
        const float* Wr = W1 + (64 + kc * 4) * 64;
#pragma unroll
        for (int kk = 0; kk < 4; ++kk) {
            float xv = xs[kk];
            const float* Wk = Wr + kk * 64;
#pragma unroll
            for (int j = 0; j < 64; ++j) acc[j] += xv * Wk[j];
        }
    }
    // ---- stage 1: k = 128..143 (edge features) ----
    const float4* ef4 = reinterpret_cast<const float4*>(ef + (size_t)ec * 16);
#pragma unroll 1
    for (int kc = 0; kc < 4; ++kc) {
        float4 x = ef4[kc];
        float xs[4] = {x.x, x.y, x.z, x.w};
        const float* Wr = W1 + (128 + kc * 4) * 64;
#pragma unroll
        for (int kk = 0; kk < 4; ++kk) {
            float xv = xs[kk];
            const float* Wk = Wr + kk * 64;
#pragma unroll
            for (int j = 0; j < 64; ++j) acc[j] += xv * Wk[j];
        }
    }

    // relu -> spill t to wave-private LDS (row-contiguous writes)
#pragma unroll
    for (int j = 0; j < 64; ++j) {
        float t = acc[j] > 0.f ? acc[j] : 0.f;
        t_lds[w][j][lane] = t;
    }
    asm volatile("s_waitcnt lgkmcnt(0)" ::: "memory");

    // ---- stage 2: m = t @ W2 + b2 ----
    float macc[64];
#pragma unroll
    for (int j = 0; j < 64; ++j) macc[j] = b2[j];
#pragma unroll 1
    for (int k = 0; k < 64; ++k) {
        float t = t_lds[w][k][lane];
        const float* Wk = W2 + k * 64;
#pragma unroll
        for (int j = 0; j < 64; ++j) macc[j] += t * Wk[j];
    }

    if (active) {
        float* ar = agg + (size_t)d * 64;
#pragma unroll
        for (int j = 0; j < 64; ++j) atomicAdd(ar + j, macc[j]);
    }
}

// ---------------------------------------------------------------------------
// GRU kernel: h = GRUCell(x=agg, h). wave = 8 nodes, lane = output j.
// 6 accumulators x 8 nodes; x/h rows staged per-wave in LDS (broadcast reads).
// In-place h update (each node's row is read before written, same wave).
// ---------------------------------------------------------------------------
__global__ __launch_bounds__(256) void gru_kernel(
    const float* __restrict__ x, float* __restrict__ h,
    const float* __restrict__ Wih, const float* __restrict__ Whh,
    const float* __restrict__ bih, const float* __restrict__ bhh, int n)
{
    __shared__ float xh[4][2][8][64];  // 8 KB: per-wave x,h rows of 8 nodes
    int w = threadIdx.x >> 6;
    int lane = threadIdx.x & 63;
    int base = (blockIdx.x * 4 + w) * 8;
    if (base >= n) return;

#pragma unroll
    for (int i = 0; i < 8; ++i) {
        int node = base + i;  // n % 8 == 0 for this problem
        xh[w][0][i][lane] = x[(size_t)node * 64 + lane];
        xh[w][1][i][lane] = h[(size_t)node * 64 + lane];
    }
    asm volatile("s_waitcnt lgkmcnt(0)" ::: "memory");

    float air[8], ahr[8], aiz[8], ahz[8], ain[8], ahn[8];
    float bir = bih[lane], biz = bih[64 + lane], bin = bih[128 + lane];
    float bhr = bhh[lane], bhz = bhh[64 + lane], bhn = bhh[128 + lane];
#pragma unroll
    for (int i = 0; i < 8; ++i) {
        air[i] = bir; aiz[i] = biz; ain[i] = bin;
        ahr[i] = bhr; ahz[i] = bhz; ahn[i] = bhn;
    }
#pragma unroll 2
    for (int k = 0; k < 64; ++k) {
        float wir = Wih[k * 192 + lane];
        float wiz = Wih[k * 192 + 64 + lane];
        float win = Wih[k * 192 + 128 + lane];
        float whr = Whh[k * 192 + lane];
        float whz = Whh[k * 192 + 64 + lane];
        float whn = Whh[k * 192 + 128 + lane];
#pragma unroll
        for (int i = 0; i < 8; ++i) {
            float xv = xh[w][0][i][k];
            float hv = xh[w][1][i][k];
            air[i] += xv * wir; aiz[i] += xv * wiz; ain[i] += xv * win;
            ahr[i] += hv * whr; ahz[i] += hv * whz; ahn[i] += hv * whn;
        }
    }
#pragma unroll
    for (int i = 0; i < 8; ++i) {
        float r = 1.f / (1.f + __expf(-(air[i] + ahr[i])));
        float z = 1.f / (1.f + __expf(-(aiz[i] + ahz[i])));
        float nn = tanhf(ain[i] + r * ahn[i]);
        float hv = xh[w][1][i][lane];
        h[(size_t)(base + i) * 64 + lane] = (1.f - z) * nn + z * hv;
    }
}

// ---------------------------------------------------------------------------
extern "C" void kernel_launch(void* const* d_in, const int* in_sizes, int n_in,
                              void* d_out, int out_size, void* d_ws, size_t ws_size,
                              hipStream_t stream)
{
    const float* nf    = (const float*)d_in[0];
    const int*   ei    = (const int*)  d_in[1];
    const float* ef    = (const float*)d_in[2];
    const float* enc_W = (const float*)d_in[3];
    const float* enc_b = (const float*)d_in[4];
    const float* mW1   = (const float*)d_in[5];
    const float* mb1   = (const float*)d_in[6];
    const float* mW2   = (const float*)d_in[7];
    const float* mb2   = (const float*)d_in[8];
    const float* gWih  = (const float*)d_in[9];
    const float* gWhh  = (const float*)d_in[10];
    const float* gbih  = (const float*)d_in[11];
    const float* gbhh  = (const float*)d_in[12];
    const float* rW1   = (const float*)d_in[13];
    const float* rb1   = (const float*)d_in[14];
    const float* rW2   = (const float*)d_in[15];
    const float* rb2   = (const float*)d_in[16];

    const int N = in_sizes[0] / HIDDIM;   // 100000
    const int E = in_sizes[2] / EDIM;     // 1200000

    float* h    = (float*)d_ws;
    float* agg  = h + (size_t)N * 64;

    const int gemmGrid = (N + 255) / 256;
    const int msgGrid  = (E + 255) / 256;
    const int gruGrid  = (N + 8 * 4 - 1) / (8 * 4);

    // encoder: h = nf @ enc_W + enc_b
    gemm64_kernel<<<gemmGrid, 256, 0, stream>>>(nf, enc_W, enc_b, h, N, 0);

    for (int l = 0; l < 3; ++l) {
        hipMemsetAsync(agg, 0, (size_t)N * 64 * sizeof(float), stream);
        msg_kernel<<<msgGrid, 256, 0, stream>>>(
            h, ei, ei + E, ef,
            mW1 + (size_t)l * 144 * 64, mb1 + (size_t)l * 64,
            mW2 + (size_t)l * 64 * 64,  mb2 + (size_t)l * 64,
            agg, E);
        gru_kernel<<<gruGrid, 256, 0, stream>>>(
            agg, h,
            gWih + (size_t)l * 64 * 192, gWhh + (size_t)l * 64 * 192,
            gbih + (size_t)l * 192,      gbhh + (size_t)l * 192, N);
    }

    // readout: out = relu(h @ rW1 + rb1) @ rW2 + rb2   (tmp reuses agg)
    gemm64_kernel<<<gemmGrid, 256, 0, stream>>>(h, rW1, rb1, agg, N, 1);
    gemm64_kernel<<<gemmGrid, 256, 0, stream>>>(agg, rW2, rb2, (float*)d_out, N, 0);
}

// Round 2
// 1617.887 us; speedup vs baseline: 8.2062x; 8.2062x over previous
//
#include <hip/hip_runtime.h>
#include <hip/hip_bf16.h>
#include <math.h>

#define HIDDIM 64
#define EDIM 16

// ---------------------------------------------------------------------------
// Generic 64x64 GEMM: out[row][j] = act( sum_k in[row][k]*W[k][j] + b[j] )
// lane = row; j fully unrolled into 64 accumulators; W/b reads are
// wave-uniform -> scalar loads. float4 stores.
// ---------------------------------------------------------------------------
__global__ __launch_bounds__(256) void gemm64_kernel(
    const float* __restrict__ in, const float* __restrict__ W,
    const float* __restrict__ b, float* __restrict__ out, int n, int relu)
{
    int row = blockIdx.x * 256 + threadIdx.x;
    if (row >= n) return;
    float acc[64];
#pragma unroll
    for (int j = 0; j < 64; ++j) acc[j] = b[j];
    const float4* in4 = reinterpret_cast<const float4*>(in + (size_t)row * 64);
#pragma unroll 1
    for (int kc = 0; kc < 16; ++kc) {
        float4 x = in4[kc];
        float xs[4] = {x.x, x.y, x.z, x.w};
        const float* Wr = W + kc * 4 * 64;
#pragma unroll
        for (int kk = 0; kk < 4; ++kk) {
            float xv = xs[kk];
            const float* Wk = Wr + kk * 64;
#pragma unroll
            for (int j = 0; j < 64; ++j) acc[j] += xv * Wk[j];
        }
    }
    float4* o4 = reinterpret_cast<float4*>(out + (size_t)row * 64);
#pragma unroll
    for (int jc = 0; jc < 16; ++jc) {
        float4 v;
        v.x = acc[jc * 4 + 0]; v.y = acc[jc * 4 + 1];
        v.z = acc[jc * 4 + 2]; v.w = acc[jc * 4 + 3];
        if (relu) {
            v.x = v.x > 0.f ? v.x : 0.f; v.y = v.y > 0.f ? v.y : 0.f;
            v.z = v.z > 0.f ? v.z : 0.f; v.w = v.w > 0.f ? v.w : 0.f;
        }
        o4[jc] = v;
    }
}

// ---------------------------------------------------------------------------
// PQ kernel: per node row: P = h@W1a ; Q = h@W1b + b1   (W1a = W1[0:64],
// W1b = W1[64:128] of the layer's msg_W1). 128 accumulators per lane.
// ---------------------------------------------------------------------------
__global__ __launch_bounds__(256) void pq_kernel(
    const float* __restrict__ h, const float* __restrict__ W1,
    const float* __restrict__ b1, float* __restrict__ P,
    float* __restrict__ QT, int n)
{
    int row = blockIdx.x * 256 + threadIdx.x;
    if (row >= n) return;
    float ap[64], aq[64];
#pragma unroll
    for (int j = 0; j < 64; ++j) { ap[j] = 0.f; aq[j] = b1[j]; }
    const float4* in4 = reinterpret_cast<const float4*>(h + (size_t)row * 64);
#pragma unroll 1
    for (int kc = 0; kc < 16; ++kc) {
        float4 x = in4[kc];
        float xs[4] = {x.x, x.y, x.z, x.w};
#pragma unroll
        for (int kk = 0; kk < 4; ++kk) {
            float xv = xs[kk];
            const float* Wa = W1 + (kc * 4 + kk) * 64;
            const float* Wb = W1 + (64 + kc * 4 + kk) * 64;
#pragma unroll
            for (int j = 0; j < 64; ++j) {
                ap[j] += xv * Wa[j];
                aq[j] += xv * Wb[j];
            }
        }
    }
    float4* p4 = reinterpret_cast<float4*>(P + (size_t)row * 64);
    float4* q4 = reinterpret_cast<float4*>(QT + (size_t)row * 64);
#pragma unroll
    for (int jc = 0; jc < 16; ++jc) {
        float4 v; v.x = ap[jc*4]; v.y = ap[jc*4+1]; v.z = ap[jc*4+2]; v.w = ap[jc*4+3];
        p4[jc] = v;
        float4 u; u.x = aq[jc*4]; u.y = aq[jc*4+1]; u.z = aq[jc*4+2]; u.w = aq[jc*4+3];
        q4[jc] = u;
    }
}

// ---------------------------------------------------------------------------
// CSR build: count -> scan -> fill
// ---------------------------------------------------------------------------
__global__ __launch_bounds__(256) void count_kernel(
    const int* __restrict__ dst, int* __restrict__ cnt, int nE)
{
    int e = blockIdx.x * 256 + threadIdx.x;
    if (e >= nE) return;
    atomicAdd(&cnt[dst[e]], 1);
}

__global__ __launch_bounds__(1024) void scan_kernel(
    const int* __restrict__ cnt, int* __restrict__ row_start,
    int* __restrict__ cursor, int nNodes, int nE)
{
    __shared__ int lds[1024];
    int tid = threadIdx.x;
    int chunk = (nNodes + 1023) >> 10;
    int b0 = tid * chunk;
    int s = 0;
    for (int c = 0; c < chunk; ++c) {
        int idx = b0 + c;
        if (idx < nNodes) s += cnt[idx];
    }
    lds[tid] = s;
    __syncthreads();
    for (int off = 1; off < 1024; off <<= 1) {
        int v = (tid >= off) ? lds[tid - off] : 0;
        __syncthreads();
        lds[tid] += v;
        __syncthreads();
    }
    int run = lds[tid] - s;  // exclusive prefix for this thread's chunk
    for (int c = 0; c < chunk; ++c) {
        int idx = b0 + c;
        if (idx < nNodes) {
            int cv = cnt[idx];
            row_start[idx] = run;
            cursor[idx] = run;
            run += cv;
        }
    }
    if (tid == 0) row_start[nNodes] = nE;
}

__global__ __launch_bounds__(256) void fill_kernel(
    const int* __restrict__ src, const int* __restrict__ dst,
    int* __restrict__ cursor, int* __restrict__ ss, int* __restrict__ se, int nE)
{
    int e = blockIdx.x * 256 + threadIdx.x;
    if (e >= nE) return;
    int d = dst[e];
    int p = atomicAdd(&cursor[d], 1);
    ss[p] = src[e];
    se[p] = e;
}

// ---------------------------------------------------------------------------
// Combine: Wci[l] = W2[l] @ Wih[l]  [64x192], b2ih[l] = b2[l] @ Wih[l] [192].
// grid = 3 layers, block = 192 (thread = output column g).
// ---------------------------------------------------------------------------
__global__ void combine_kernel(
    const float* __restrict__ mW2, const float* __restrict__ mb2,
    const float* __restrict__ gWih, float* __restrict__ Wci,
    float* __restrict__ b2ih)
{
    int l = blockIdx.x;
    int g = threadIdx.x;
    const float* W2  = mW2  + (size_t)l * 64 * 64;
    const float* Wih = gWih + (size_t)l * 64 * 192;
    const float* b2  = mb2  + (size_t)l * 64;
    float acc[64];
#pragma unroll
    for (int k = 0; k < 64; ++k) acc[k] = 0.f;
    float bacc = 0.f;
#pragma unroll 1
    for (int j = 0; j < 64; ++j) {
        float w = Wih[j * 192 + g];
        bacc += b2[j] * w;
#pragma unroll
        for (int k = 0; k < 64; ++k) acc[k] += W2[k * 64 + j] * w;
    }
    float* o = Wci + (size_t)l * 64 * 192;
#pragma unroll
    for (int k = 0; k < 64; ++k) o[k * 192 + g] = acc[k];
    b2ih[l * 192 + g] = bacc;
}

// ---------------------------------------------------------------------------
// Edge aggregation (node-centric, zero atomics):
//   T[n] = sum over incoming edges e of relu(P[src[e]] + Q[n] + ef[e]@W1c)
// wave = node (grid-stride), lane = channel j. Q buffer is overwritten with T
// (safe: Q[n] only read by wave n, before the write). src/eid/ef reads are
// wave-uniform -> scalar loads; P row gather is coalesced.
// ---------------------------------------------------------------------------
__global__ __launch_bounds__(256) void edge_agg_kernel(
    const float* __restrict__ P, float* QT, const float* __restrict__ ef,
    const float* __restrict__ W1c, const int* __restrict__ sorted_src,
    const int* __restrict__ sorted_eid, const int* __restrict__ row_start,
    int nNodes)
{
    int wg = blockIdx.x * 4 + (threadIdx.x >> 6);
    wg = __builtin_amdgcn_readfirstlane(wg);
    int lane = threadIdx.x & 63;
    int nw = gridDim.x * 4;

    float w1c[16];
#pragma unroll
    for (int k = 0; k < 16; ++k) w1c[k] = W1c[k * 64 + lane];

    for (int n = wg; n < nNodes; n += nw) {
        int rs = row_start[n];
        int re = row_start[n + 1];
        float q = QT[(size_t)n * 64 + lane];
        float tacc = 0.f;
        for (int i = rs; i < re; ++i) {
            int s = sorted_src[i];
            int e = sorted_eid[i];
            const float* efr = ef + (size_t)e * 16;
            const float* pr  = P + (size_t)s * 64;
            float r0 = 0.f;
#pragma unroll
            for (int k = 0; k < 16; ++k) r0 += efr[k] * w1c[k];
            float t = pr[lane] + q + r0;
            t = t > 0.f ? t : 0.f;
            tacc += t;
        }
        QT[(size_t)n * 64 + lane] = tacc;
    }
}

// ---------------------------------------------------------------------------
// GRU kernel with folded stage-2:  x_eff = T@Wci + deg*b2ih  (Wci = W2@Wih,
// b2ih = b2@Wih precomputed).  gi = x_eff + bih ; gh = h@Whh + bhh.
// wave = 8 nodes, lane = channel j.
// ---------------------------------------------------------------------------
__global__ __launch_bounds__(256) void gru_kernel(
    const float* __restrict__ T, float* __restrict__ h,
    const float* __restrict__ Wci, const float* __restrict__ Whh,
    const float* __restrict__ bih, const float* __restrict__ bhh,
    const float* __restrict__ b2ih, const int* __restrict__ row_start, int n)
{
    __shared__ float xh[4][2][8][64];
    int w = threadIdx.x >> 6;
    int lane = threadIdx.x & 63;
    int base = (blockIdx.x * 4 + w) * 8;
    if (base >= n) return;

#pragma unroll
    for (int i = 0; i < 8; ++i) {
        int node = base + i;
        xh[w][0][i][lane] = T[(size_t)node * 64 + lane];
        xh[w][1][i][lane] = h[(size_t)node * 64 + lane];
    }
    asm volatile("s_waitcnt lgkmcnt(0)" ::: "memory");

    float air[8], ahr[8], aiz[8], ahz[8], ain[8], ahn[8];
    float bir = bih[lane], biz = bih[64 + lane], bin = bih[128 + lane];
    float bhr = bhh[lane], bhz = bhh[64 + lane], bhn = bhh[128 + lane];
    float b2r = b2ih[lane], b2z = b2ih[64 + lane], b2n = b2ih[128 + lane];
#pragma unroll
    for (int i = 0; i < 8; ++i) {
        int node = base + i;
        float dg = (float)(row_start[node + 1] - row_start[node]);
        air[i] = bir + dg * b2r; aiz[i] = biz + dg * b2z; ain[i] = bin + dg * b2n;
        ahr[i] = bhr; ahz[i] = bhz; ahn[i] = bhn;
    }
#pragma unroll 2
    for (int k = 0; k < 64; ++k) {
        float wir = Wci[k * 192 + lane];
        float wiz = Wci[k * 192 + 64 + lane];
        float win = Wci[k * 192 + 128 + lane];
        float whr = Whh[k * 192 + lane];
        float whz = Whh[k * 192 + 64 + lane];
        float whn = Whh[k * 192 + 128 + lane];
#pragma unroll
        for (int i = 0; i < 8; ++i) {
            float xv = xh[w][0][i][k];
            float hv = xh[w][1][i][k];
            air[i] += xv * wir; aiz[i] += xv * wiz; ain[i] += xv * win;
            ahr[i] += hv * whr; ahz[i] += hv * whz; ahn[i] += hv * whn;
        }
    }
#pragma unroll
    for (int i = 0; i < 8; ++i) {
        float r = 1.f / (1.f + __expf(-(air[i] + ahr[i])));
        float z = 1.f / (1.f + __expf(-(aiz[i] + ahz[i])));
        float nn = tanhf(ain[i] + r * ahn[i]);
        float hv = xh[w][1][i][lane];
        h[(size_t)(base + i) * 64 + lane] = (1.f - z) * nn + z * hv;
    }
}

// ---------------------------------------------------------------------------
extern "C" void kernel_launch(void* const* d_in, const int* in_sizes, int n_in,
                              void* d_out, int out_size, void* d_ws, size_t ws_size,
                              hipStream_t stream)
{
    const float* nf    = (const float*)d_in[0];
    const int*   ei    = (const int*)  d_in[1];
    const float* ef    = (const float*)d_in[2];
    const float* enc_W = (const float*)d_in[3];
    const float* enc_b = (const float*)d_in[4];
    const float* mW1   = (const float*)d_in[5];
    const float* mb1   = (const float*)d_in[6];
    const float* mW2   = (const float*)d_in[7];
    const float* mb2   = (const float*)d_in[8];
    const float* gWih  = (const float*)d_in[9];
    const float* gWhh  = (const float*)d_in[10];
    const float* gbih  = (const float*)d_in[11];
    const float* gbhh  = (const float*)d_in[12];
    const float* rW1   = (const float*)d_in[13];
    const float* rb1   = (const float*)d_in[14];
    const float* rW2   = (const float*)d_in[15];
    const float* rb2   = (const float*)d_in[16];

    const int N = in_sizes[0] / HIDDIM;   // 100000
    const int E = in_sizes[2] / EDIM;     // 1200000

    // workspace layout (floats/ints)
    char* wsB = (char*)d_ws;
    float* h         = (float*)wsB;                 wsB += (size_t)N * 64 * sizeof(float);
    float* P         = (float*)wsB;                 wsB += (size_t)N * 64 * sizeof(float);
    float* QT        = (float*)wsB;                 wsB += (size_t)N * 64 * sizeof(float);
    int*   row_start = (int*)wsB;                   wsB += (size_t)(N + 1) * sizeof(int);
    int*   cursor    = (int*)wsB;                   wsB += (size_t)N * sizeof(int);
    int*   cnt       = (int*)wsB;                   wsB += (size_t)N * sizeof(int);
    int*   s_src     = (int*)wsB;                   wsB += (size_t)E * sizeof(int);
    int*   s_eid     = (int*)wsB;                   wsB += (size_t)E * sizeof(int);
    float* Wci       = (float*)wsB;                 wsB += (size_t)3 * 64 * 192 * sizeof(float);
    float* b2ih      = (float*)wsB;                 wsB += (size_t)3 * 192 * sizeof(float);

    const int gemmGrid = (N + 255) / 256;
    const int edgeGrid = (E + 255) / 256;
    const int gruGrid  = (N + 31) / 32;

    // encoder: h = nf @ enc_W + enc_b
    gemm64_kernel<<<gemmGrid, 256, 0, stream>>>(nf, enc_W, enc_b, h, N, 0);

    // CSR build (once per call)
    hipMemsetAsync(cnt, 0, (size_t)N * sizeof(int), stream);
    count_kernel<<<edgeGrid, 256, 0, stream>>>(ei + E, cnt, E);
    scan_kernel<<<1, 1024, 0, stream>>>(cnt, row_start, cursor, N, E);
    fill_kernel<<<edgeGrid, 256, 0, stream>>>(ei, ei + E, cursor, s_src, s_eid, E);

    // folded GRU input weights (once per call)
    combine_kernel<<<3, 192, 0, stream>>>(mW2, mb2, gWih, Wci, b2ih);

    for (int l = 0; l < 3; ++l) {
        const float* W1  = mW1 + (size_t)l * 144 * 64;
        const float* W1c = W1 + 128 * 64;
        pq_kernel<<<gemmGrid, 256, 0, stream>>>(h, W1, mb1 + (size_t)l * 64, P, QT, N);
        edge_agg_kernel<<<2048, 256, 0, stream>>>(P, QT, ef, W1c, s_src, s_eid,
                                                  row_start, N);
        gru_kernel<<<gruGrid, 256, 0, stream>>>(
            QT, h,
            Wci + (size_t)l * 64 * 192, gWhh + (size_t)l * 64 * 192,
            gbih + (size_t)l * 192,     gbhh + (size_t)l * 192,
            b2ih + (size_t)l * 192,     row_start, N);
    }

    // readout: out = relu(h @ rW1 + rb1) @ rW2 + rb2   (tmp reuses P)
    gemm64_kernel<<<gemmGrid, 256, 0, stream>>>(h, rW1, rb1, P, N, 1);
    gemm64_kernel<<<gemmGrid, 256, 0, stream>>>(P, rW2, rb2, (float*)d_out, N, 0);
}

// Round 3
// 1389.612 us; speedup vs baseline: 9.5542x; 1.1643x over previous
//
#include <hip/hip_runtime.h>
#include <hip/hip_bf16.h>
#include <math.h>

#define HIDDIM 64
#define EDIM 16

// ---------------------------------------------------------------------------
// Generic 64x64 GEMM: out[row][j] = act( sum_k in[row][k]*W[k][j] + b[j] )
// lane = row; j fully unrolled into 64 accumulators; W/b reads are
// wave-uniform -> scalar loads. float4 stores.
// ---------------------------------------------------------------------------
__global__ __launch_bounds__(256) void gemm64_kernel(
    const float* __restrict__ in, const float* __restrict__ W,
    const float* __restrict__ b, float* __restrict__ out, int n, int relu)
{
    int row = blockIdx.x * 256 + threadIdx.x;
    if (row >= n) return;
    float acc[64];
#pragma unroll
    for (int j = 0; j < 64; ++j) acc[j] = b[j];
    const float4* in4 = reinterpret_cast<const float4*>(in + (size_t)row * 64);
#pragma unroll 1
    for (int kc = 0; kc < 16; ++kc) {
        float4 x = in4[kc];
        float xs[4] = {x.x, x.y, x.z, x.w};
        const float* Wr = W + kc * 4 * 64;
#pragma unroll
        for (int kk = 0; kk < 4; ++kk) {
            float xv = xs[kk];
            const float* Wk = Wr + kk * 64;
#pragma unroll
            for (int j = 0; j < 64; ++j) acc[j] += xv * Wk[j];
        }
    }
    float4* o4 = reinterpret_cast<float4*>(out + (size_t)row * 64);
#pragma unroll
    for (int jc = 0; jc < 16; ++jc) {
        float4 v;
        v.x = acc[jc * 4 + 0]; v.y = acc[jc * 4 + 1];
        v.z = acc[jc * 4 + 2]; v.w = acc[jc * 4 + 3];
        if (relu) {
            v.x = v.x > 0.f ? v.x : 0.f; v.y = v.y > 0.f ? v.y : 0.f;
            v.z = v.z > 0.f ? v.z : 0.f; v.w = v.w > 0.f ? v.w : 0.f;
        }
        o4[jc] = v;
    }
}

// ---------------------------------------------------------------------------
// PQ kernel: per node row: P = h@W1a ; Q = h@W1b + b1.
// ---------------------------------------------------------------------------
__global__ __launch_bounds__(256) void pq_kernel(
    const float* __restrict__ h, const float* __restrict__ W1,
    const float* __restrict__ b1, float* __restrict__ P,
    float* __restrict__ QT, int n)
{
    int row = blockIdx.x * 256 + threadIdx.x;
    if (row >= n) return;
    float ap[64], aq[64];
#pragma unroll
    for (int j = 0; j < 64; ++j) { ap[j] = 0.f; aq[j] = b1[j]; }
    const float4* in4 = reinterpret_cast<const float4*>(h + (size_t)row * 64);
#pragma unroll 1
    for (int kc = 0; kc < 16; ++kc) {
        float4 x = in4[kc];
        float xs[4] = {x.x, x.y, x.z, x.w};
#pragma unroll
        for (int kk = 0; kk < 4; ++kk) {
            float xv = xs[kk];
            const float* Wa = W1 + (kc * 4 + kk) * 64;
            const float* Wb = W1 + (64 + kc * 4 + kk) * 64;
#pragma unroll
            for (int j = 0; j < 64; ++j) {
                ap[j] += xv * Wa[j];
                aq[j] += xv * Wb[j];
            }
        }
    }
    float4* p4 = reinterpret_cast<float4*>(P + (size_t)row * 64);
    float4* q4 = reinterpret_cast<float4*>(QT + (size_t)row * 64);
#pragma unroll
    for (int jc = 0; jc < 16; ++jc) {
        float4 v; v.x = ap[jc*4]; v.y = ap[jc*4+1]; v.z = ap[jc*4+2]; v.w = ap[jc*4+3];
        p4[jc] = v;
        float4 u; u.x = aq[jc*4]; u.y = aq[jc*4+1]; u.z = aq[jc*4+2]; u.w = aq[jc*4+3];
        q4[jc] = u;
    }
}

// ---------------------------------------------------------------------------
// CSR build: count -> (3-stage device-wide scan) -> fill
// ---------------------------------------------------------------------------
__global__ __launch_bounds__(256) void count_kernel(
    const int* __restrict__ dst, int* __restrict__ cnt, int nE)
{
    int e = blockIdx.x * 256 + threadIdx.x;
    if (e >= nE) return;
    atomicAdd(&cnt[dst[e]], 1);
}

// stage 1: per-block sum of a 256-chunk of cnt
__global__ __launch_bounds__(256) void partial_kernel(
    const int* __restrict__ cnt, int* __restrict__ partial, int nNodes)
{
    __shared__ int lds[256];
    int i = blockIdx.x * 256 + threadIdx.x;
    int v = (i < nNodes) ? cnt[i] : 0;
    lds[threadIdx.x] = v;
    __syncthreads();
#pragma unroll
    for (int off = 128; off > 0; off >>= 1) {
        if (threadIdx.x < off) lds[threadIdx.x] += lds[threadIdx.x + off];
        __syncthreads();
    }
    if (threadIdx.x == 0) partial[blockIdx.x] = lds[0];
}

// stage 2: single-block exclusive scan of the block partials (nb <= 1024)
__global__ __launch_bounds__(1024) void scan_partials_kernel(
    int* __restrict__ partial, int* __restrict__ row_start, int nb,
    int nNodes, int nE)
{
    __shared__ int lds[1024];
    int tid = threadIdx.x;
    int v = (tid < nb) ? partial[tid] : 0;
    lds[tid] = v;
    __syncthreads();
    for (int off = 1; off < 1024; off <<= 1) {
        int t = (tid >= off) ? lds[tid - off] : 0;
        __syncthreads();
        lds[tid] += t;
        __syncthreads();
    }
    if (tid < nb) partial[tid] = lds[tid] - v;  // exclusive block offset
    if (tid == 0) row_start[nNodes] = nE;
}

// stage 3: per-block exclusive scan of its chunk + block offset
__global__ __launch_bounds__(256) void scan_blocks_kernel(
    const int* __restrict__ cnt, const int* __restrict__ partial,
    int* __restrict__ row_start, int* __restrict__ cursor, int nNodes)
{
    __shared__ int lds[256];
    int i = blockIdx.x * 256 + threadIdx.x;
    int v = (i < nNodes) ? cnt[i] : 0;
    lds[threadIdx.x] = v;
    __syncthreads();
    for (int off = 1; off < 256; off <<= 1) {
        int t = (threadIdx.x >= off) ? lds[threadIdx.x - off] : 0;
        __syncthreads();
        lds[threadIdx.x] += t;
        __syncthreads();
    }
    if (i < nNodes) {
        int excl = partial[blockIdx.x] + lds[threadIdx.x] - v;
        row_start[i] = excl;
        cursor[i] = excl;
    }
}

__global__ __launch_bounds__(256) void fill_kernel(
    const int* __restrict__ src, const int* __restrict__ dst,
    int* __restrict__ cursor, int* __restrict__ ss, int* __restrict__ se, int nE)
{
    int e = blockIdx.x * 256 + threadIdx.x;
    if (e >= nE) return;
    int d = dst[e];
    int p = atomicAdd(&cursor[d], 1);
    ss[p] = src[e];
    se[p] = e;
}

// ---------------------------------------------------------------------------
// Combine: Wci[l] = W2[l] @ Wih[l]  [64x192], b2ih[l] = b2[l] @ Wih[l] [192].
// ---------------------------------------------------------------------------
__global__ void combine_kernel(
    const float* __restrict__ mW2, const float* __restrict__ mb2,
    const float* __restrict__ gWih, float* __restrict__ Wci,
    float* __restrict__ b2ih)
{
    int l = blockIdx.x;
    int g = threadIdx.x;
    const float* W2  = mW2  + (size_t)l * 64 * 64;
    const float* Wih = gWih + (size_t)l * 64 * 192;
    const float* b2  = mb2  + (size_t)l * 64;
    float acc[64];
#pragma unroll
    for (int k = 0; k < 64; ++k) acc[k] = 0.f;
    float bacc = 0.f;
#pragma unroll 1
    for (int j = 0; j < 64; ++j) {
        float w = Wih[j * 192 + g];
        bacc += b2[j] * w;
#pragma unroll
        for (int k = 0; k < 64; ++k) acc[k] += W2[k * 64 + j] * w;
    }
    float* o = Wci + (size_t)l * 64 * 192;
#pragma unroll
    for (int k = 0; k < 64; ++k) o[k * 192 + g] = acc[k];
    b2ih[l * 192 + g] = bacc;
}

// ---------------------------------------------------------------------------
// Edge aggregation (node-centric, zero atomics):
//   T[n] = sum over incoming edges e of relu(P[src[e]] + Q[n] + ef[e]@W1c)
// wave = node (grid-stride), lane = channel j. Q overwritten with T.
// ---------------------------------------------------------------------------
__global__ __launch_bounds__(256) void edge_agg_kernel(
    const float* __restrict__ P, float* QT, const float* __restrict__ ef,
    const float* __restrict__ W1c, const int* __restrict__ sorted_src,
    const int* __restrict__ sorted_eid, const int* __restrict__ row_start,
    int nNodes)
{
    int wg = blockIdx.x * 4 + (threadIdx.x >> 6);
    wg = __builtin_amdgcn_readfirstlane(wg);
    int lane = threadIdx.x & 63;
    int nw = gridDim.x * 4;

    float w1c[16];
#pragma unroll
    for (int k = 0; k < 16; ++k) w1c[k] = W1c[k * 64 + lane];

    for (int n = wg; n < nNodes; n += nw) {
        int rs = row_start[n];
        int re = row_start[n + 1];
        float q = QT[(size_t)n * 64 + lane];
        float tacc = 0.f;
        for (int i = rs; i < re; ++i) {
            int s = sorted_src[i];
            int e = sorted_eid[i];
            const float* efr = ef + (size_t)e * 16;
            const float* pr  = P + (size_t)s * 64;
            float r0 = 0.f;
#pragma unroll
            for (int k = 0; k < 16; ++k) r0 += efr[k] * w1c[k];
            float t = pr[lane] + q + r0;
            t = t > 0.f ? t : 0.f;
            tacc += t;
        }
        QT[(size_t)n * 64 + lane] = tacc;
    }
}

// ---------------------------------------------------------------------------
// GRU kernel with folded stage-2:  x_eff = T@Wci + deg*b2ih.
// ---------------------------------------------------------------------------
__global__ __launch_bounds__(256) void gru_kernel(
    const float* __restrict__ T, float* __restrict__ h,
    const float* __restrict__ Wci, const float* __restrict__ Whh,
    const float* __restrict__ bih, const float* __restrict__ bhh,
    const float* __restrict__ b2ih, const int* __restrict__ row_start, int n)
{
    __shared__ float xh[4][2][8][64];
    int w = threadIdx.x >> 6;
    int lane = threadIdx.x & 63;
    int base = (blockIdx.x * 4 + w) * 8;
    if (base >= n) return;

#pragma unroll
    for (int i = 0; i < 8; ++i) {
        int node = base + i;
        xh[w][0][i][lane] = T[(size_t)node * 64 + lane];
        xh[w][1][i][lane] = h[(size_t)node * 64 + lane];
    }
    asm volatile("s_waitcnt lgkmcnt(0)" ::: "memory");

    float air[8], ahr[8], aiz[8], ahz[8], ain[8], ahn[8];
    float bir = bih[lane], biz = bih[64 + lane], bin = bih[128 + lane];
    float bhr = bhh[lane], bhz = bhh[64 + lane], bhn = bhh[128 + lane];
    float b2r = b2ih[lane], b2z = b2ih[64 + lane], b2n = b2ih[128 + lane];
#pragma unroll
    for (int i = 0; i < 8; ++i) {
        int node = base + i;
        float dg = (float)(row_start[node + 1] - row_start[node]);
        air[i] = bir + dg * b2r; aiz[i] = biz + dg * b2z; ain[i] = bin + dg * b2n;
        ahr[i] = bhr; ahz[i] = bhz; ahn[i] = bhn;
    }
#pragma unroll 2
    for (int k = 0; k < 64; ++k) {
        float wir = Wci[k * 192 + lane];
        float wiz = Wci[k * 192 + 64 + lane];
        float win = Wci[k * 192 + 128 + lane];
        float whr = Whh[k * 192 + lane];
        float whz = Whh[k * 192 + 64 + lane];
        float whn = Whh[k * 192 + 128 + lane];
#pragma unroll
        for (int i = 0; i < 8; ++i) {
            float xv = xh[w][0][i][k];
            float hv = xh[w][1][i][k];
            air[i] += xv * wir; aiz[i] += xv * wiz; ain[i] += xv * win;
            ahr[i] += hv * whr; ahz[i] += hv * whz; ahn[i] += hv * whn;
        }
    }
#pragma unroll
    for (int i = 0; i < 8; ++i) {
        float r = 1.f / (1.f + __expf(-(air[i] + ahr[i])));
        float z = 1.f / (1.f + __expf(-(aiz[i] + ahz[i])));
        float nn = tanhf(ain[i] + r * ahn[i]);
        float hv = xh[w][1][i][lane];
        h[(size_t)(base + i) * 64 + lane] = (1.f - z) * nn + z * hv;
    }
}

// ---------------------------------------------------------------------------
extern "C" void kernel_launch(void* const* d_in, const int* in_sizes, int n_in,
                              void* d_out, int out_size, void* d_ws, size_t ws_size,
                              hipStream_t stream)
{
    const float* nf    = (const float*)d_in[0];
    const int*   ei    = (const int*)  d_in[1];
    const float* ef    = (const float*)d_in[2];
    const float* enc_W = (const float*)d_in[3];
    const float* enc_b = (const float*)d_in[4];
    const float* mW1   = (const float*)d_in[5];
    const float* mb1   = (const float*)d_in[6];
    const float* mW2   = (const float*)d_in[7];
    const float* mb2   = (const float*)d_in[8];
    const float* gWih  = (const float*)d_in[9];
    const float* gWhh  = (const float*)d_in[10];
    const float* gbih  = (const float*)d_in[11];
    const float* gbhh  = (const float*)d_in[12];
    const float* rW1   = (const float*)d_in[13];
    const float* rb1   = (const float*)d_in[14];
    const float* rW2   = (const float*)d_in[15];
    const float* rb2   = (const float*)d_in[16];

    const int N = in_sizes[0] / HIDDIM;   // 100000
    const int E = in_sizes[2] / EDIM;     // 1200000

    // workspace layout
    char* wsB = (char*)d_ws;
    float* h         = (float*)wsB;                 wsB += (size_t)N * 64 * sizeof(float);
    float* P         = (float*)wsB;                 wsB += (size_t)N * 64 * sizeof(float);
    float* QT        = (float*)wsB;                 wsB += (size_t)N * 64 * sizeof(float);
    int*   row_start = (int*)wsB;                   wsB += (size_t)(N + 1) * sizeof(int);
    int*   cursor    = (int*)wsB;                   wsB += (size_t)N * sizeof(int);
    int*   cnt       = (int*)wsB;                   wsB += (size_t)N * sizeof(int);
    int*   partial   = (int*)wsB;                   wsB += (size_t)1024 * sizeof(int);
    int*   s_src     = (int*)wsB;                   wsB += (size_t)E * sizeof(int);
    int*   s_eid     = (int*)wsB;                   wsB += (size_t)E * sizeof(int);
    float* Wci       = (float*)wsB;                 wsB += (size_t)3 * 64 * 192 * sizeof(float);
    float* b2ih      = (float*)wsB;                 wsB += (size_t)3 * 192 * sizeof(float);

    const int gemmGrid = (N + 255) / 256;
    const int edgeGrid = (E + 255) / 256;
    const int gruGrid  = (N + 31) / 32;
    const int nScanBlk = (N + 255) / 256;  // 391 <= 1024

    // encoder: h = nf @ enc_W + enc_b
    gemm64_kernel<<<gemmGrid, 256, 0, stream>>>(nf, enc_W, enc_b, h, N, 0);

    // CSR build (once per call)
    hipMemsetAsync(cnt, 0, (size_t)N * sizeof(int), stream);
    count_kernel<<<edgeGrid, 256, 0, stream>>>(ei + E, cnt, E);
    partial_kernel<<<nScanBlk, 256, 0, stream>>>(cnt, partial, N);
    scan_partials_kernel<<<1, 1024, 0, stream>>>(partial, row_start, nScanBlk, N, E);
    scan_blocks_kernel<<<nScanBlk, 256, 0, stream>>>(cnt, partial, row_start, cursor, N);
    fill_kernel<<<edgeGrid, 256, 0, stream>>>(ei, ei + E, cursor, s_src, s_eid, E);

    // folded GRU input weights (once per call)
    combine_kernel<<<3, 192, 0, stream>>>(mW2, mb2, gWih, Wci, b2ih);

    for (int l = 0; l < 3; ++l) {
        const float* W1  = mW1 + (size_t)l * 144 * 64;
        const float* W1c = W1 + 128 * 64;
        pq_kernel<<<gemmGrid, 256, 0, stream>>>(h, W1, mb1 + (size_t)l * 64, P, QT, N);
        edge_agg_kernel<<<2048, 256, 0, stream>>>(P, QT, ef, W1c, s_src, s_eid,
                                                  row_start, N);
        gru_kernel<<<gruGrid, 256, 0, stream>>>(
            QT, h,
            Wci + (size_t)l * 64 * 192, gWhh + (size_t)l * 64 * 192,
            gbih + (size_t)l * 192,     gbhh + (size_t)l * 192,
            b2ih + (size_t)l * 192,     row_start, N);
    }

    // readout
    gemm64_kernel<<<gemmGrid, 256, 0, stream>>>(h, rW1, rb1, P, N, 1);
    gemm64_kernel<<<gemmGrid, 256, 0, stream>>>(P, rW2, rb2, (float*)d_out, N, 0);
}

// Round 4
// 1263.236 us; speedup vs baseline: 10.5100x; 1.1000x over previous
//
#include <hip/hip_runtime.h>
#include <hip/hip_bf16.h>
#include <math.h>

#define HIDDIM 64
#define EDIM 16

// ---------------------------------------------------------------------------
// Generic 64x64 GEMM: out[row][j] = act( sum_k in[row][k]*W[k][j] + b[j] )
// ---------------------------------------------------------------------------
__global__ __launch_bounds__(256) void gemm64_kernel(
    const float* __restrict__ in, const float* __restrict__ W,
    const float* __restrict__ b, float* __restrict__ out, int n, int relu)
{
    int row = blockIdx.x * 256 + threadIdx.x;
    if (row >= n) return;
    float acc[64];
#pragma unroll
    for (int j = 0; j < 64; ++j) acc[j] = b[j];
    const float4* in4 = reinterpret_cast<const float4*>(in + (size_t)row * 64);
#pragma unroll 1
    for (int kc = 0; kc < 16; ++kc) {
        float4 x = in4[kc];
        float xs[4] = {x.x, x.y, x.z, x.w};
        const float* Wr = W + kc * 4 * 64;
#pragma unroll
        for (int kk = 0; kk < 4; ++kk) {
            float xv = xs[kk];
            const float* Wk = Wr + kk * 64;
#pragma unroll
            for (int j = 0; j < 64; ++j) acc[j] += xv * Wk[j];
        }
    }
    float4* o4 = reinterpret_cast<float4*>(out + (size_t)row * 64);
#pragma unroll
    for (int jc = 0; jc < 16; ++jc) {
        float4 v;
        v.x = acc[jc * 4 + 0]; v.y = acc[jc * 4 + 1];
        v.z = acc[jc * 4 + 2]; v.w = acc[jc * 4 + 3];
        if (relu) {
            v.x = v.x > 0.f ? v.x : 0.f; v.y = v.y > 0.f ? v.y : 0.f;
            v.z = v.z > 0.f ? v.z : 0.f; v.w = v.w > 0.f ? v.w : 0.f;
        }
        o4[jc] = v;
    }
}

// ---------------------------------------------------------------------------
// PQ kernel: per node row: P = h@W1a ; Q = h@W1b + b1.
// ---------------------------------------------------------------------------
__global__ __launch_bounds__(256) void pq_kernel(
    const float* __restrict__ h, const float* __restrict__ W1,
    const float* __restrict__ b1, float* __restrict__ P,
    float* __restrict__ QT, int n)
{
    int row = blockIdx.x * 256 + threadIdx.x;
    if (row >= n) return;
    float ap[64], aq[64];
#pragma unroll
    for (int j = 0; j < 64; ++j) { ap[j] = 0.f; aq[j] = b1[j]; }
    const float4* in4 = reinterpret_cast<const float4*>(h + (size_t)row * 64);
#pragma unroll 1
    for (int kc = 0; kc < 16; ++kc) {
        float4 x = in4[kc];
        float xs[4] = {x.x, x.y, x.z, x.w};
#pragma unroll
        for (int kk = 0; kk < 4; ++kk) {
            float xv = xs[kk];
            const float* Wa = W1 + (kc * 4 + kk) * 64;
            const float* Wb = W1 + (64 + kc * 4 + kk) * 64;
#pragma unroll
            for (int j = 0; j < 64; ++j) {
                ap[j] += xv * Wa[j];
                aq[j] += xv * Wb[j];
            }
        }
    }
    float4* p4 = reinterpret_cast<float4*>(P + (size_t)row * 64);
    float4* q4 = reinterpret_cast<float4*>(QT + (size_t)row * 64);
#pragma unroll
    for (int jc = 0; jc < 16; ++jc) {
        float4 v; v.x = ap[jc*4]; v.y = ap[jc*4+1]; v.z = ap[jc*4+2]; v.w = ap[jc*4+3];
        p4[jc] = v;
        float4 u; u.x = aq[jc*4]; u.y = aq[jc*4+1]; u.z = aq[jc*4+2]; u.w = aq[jc*4+3];
        q4[jc] = u;
    }
}

// ---------------------------------------------------------------------------
// CSR build: count -> (3-stage device-wide scan) -> fill(+ef permute)
// ---------------------------------------------------------------------------
__global__ __launch_bounds__(256) void count_kernel(
    const int* __restrict__ dst, int* __restrict__ cnt, int nE)
{
    int e = blockIdx.x * 256 + threadIdx.x;
    if (e >= nE) return;
    atomicAdd(&cnt[dst[e]], 1);
}

__global__ __launch_bounds__(256) void partial_kernel(
    const int* __restrict__ cnt, int* __restrict__ partial, int nNodes)
{
    __shared__ int lds[256];
    int i = blockIdx.x * 256 + threadIdx.x;
    int v = (i < nNodes) ? cnt[i] : 0;
    lds[threadIdx.x] = v;
    __syncthreads();
#pragma unroll
    for (int off = 128; off > 0; off >>= 1) {
        if (threadIdx.x < off) lds[threadIdx.x] += lds[threadIdx.x + off];
        __syncthreads();
    }
    if (threadIdx.x == 0) partial[blockIdx.x] = lds[0];
}

__global__ __launch_bounds__(1024) void scan_partials_kernel(
    int* __restrict__ partial, int* __restrict__ row_start, int nb,
    int nNodes, int nE)
{
    __shared__ int lds[1024];
    int tid = threadIdx.x;
    int v = (tid < nb) ? partial[tid] : 0;
    lds[tid] = v;
    __syncthreads();
    for (int off = 1; off < 1024; off <<= 1) {
        int t = (tid >= off) ? lds[tid - off] : 0;
        __syncthreads();
        lds[tid] += t;
        __syncthreads();
    }
    if (tid < nb) partial[tid] = lds[tid] - v;
    if (tid == 0) row_start[nNodes] = nE;
}

__global__ __launch_bounds__(256) void scan_blocks_kernel(
    const int* __restrict__ cnt, const int* __restrict__ partial,
    int* __restrict__ row_start, int* __restrict__ cursor, int nNodes)
{
    __shared__ int lds[256];
    int i = blockIdx.x * 256 + threadIdx.x;
    int v = (i < nNodes) ? cnt[i] : 0;
    lds[threadIdx.x] = v;
    __syncthreads();
    for (int off = 1; off < 256; off <<= 1) {
        int t = (threadIdx.x >= off) ? lds[threadIdx.x - off] : 0;
        __syncthreads();
        lds[threadIdx.x] += t;
        __syncthreads();
    }
    if (i < nNodes) {
        int excl = partial[blockIdx.x] + lds[threadIdx.x] - v;
        row_start[i] = excl;
        cursor[i] = excl;
    }
}

// fill: CSR position + permute src and the 64B ef row into CSR order
__global__ __launch_bounds__(256) void fill_kernel(
    const int* __restrict__ src, const int* __restrict__ dst,
    const float* __restrict__ ef, int* __restrict__ cursor,
    int* __restrict__ ss, float* __restrict__ sef, int nE)
{
    int e = blockIdx.x * 256 + threadIdx.x;
    if (e >= nE) return;
    int d = dst[e];
    int p = atomicAdd(&cursor[d], 1);
    ss[p] = src[e];
    const float4* er = reinterpret_cast<const float4*>(ef + (size_t)e * 16);
    float4* sr = reinterpret_cast<float4*>(sef + (size_t)p * 16);
    float4 a0 = er[0], a1 = er[1], a2 = er[2], a3 = er[3];
    sr[0] = a0; sr[1] = a1; sr[2] = a2; sr[3] = a3;
}

// ---------------------------------------------------------------------------
// Combine: Wci[l] = W2[l] @ Wih[l]  [64x192], b2ih[l] = b2[l] @ Wih[l] [192].
// ---------------------------------------------------------------------------
__global__ void combine_kernel(
    const float* __restrict__ mW2, const float* __restrict__ mb2,
    const float* __restrict__ gWih, float* __restrict__ Wci,
    float* __restrict__ b2ih)
{
    int l = blockIdx.x;
    int g = threadIdx.x;
    const float* W2  = mW2  + (size_t)l * 64 * 64;
    const float* Wih = gWih + (size_t)l * 64 * 192;
    const float* b2  = mb2  + (size_t)l * 64;
    float acc[64];
#pragma unroll
    for (int k = 0; k < 64; ++k) acc[k] = 0.f;
    float bacc = 0.f;
#pragma unroll 1
    for (int j = 0; j < 64; ++j) {
        float w = Wih[j * 192 + g];
        bacc += b2[j] * w;
#pragma unroll
        for (int k = 0; k < 64; ++k) acc[k] += W2[k * 64 + j] * w;
    }
    float* o = Wci + (size_t)l * 64 * 192;
#pragma unroll
    for (int k = 0; k < 64; ++k) o[k * 192 + g] = acc[k];
    b2ih[l * 192 + g] = bacc;
}

// ---------------------------------------------------------------------------
// Edge aggregation (node-centric, zero atomics, 4-way edge ILP):
//   T[n] = sum_e relu(P[src[e]] + Q[n] + sef[p]@W1c)
// sef is in CSR order -> sequential wave-uniform reads. 4 independent P-row
// gathers in flight per iteration.
// ---------------------------------------------------------------------------
__global__ __launch_bounds__(256) void edge_agg_kernel(
    const float* __restrict__ P, float* QT, const float* __restrict__ sef,
    const float* __restrict__ W1c, const int* __restrict__ sorted_src,
    const int* __restrict__ row_start, int nNodes)
{
    int wg = blockIdx.x * 4 + (threadIdx.x >> 6);
    wg = __builtin_amdgcn_readfirstlane(wg);
    int lane = threadIdx.x & 63;
    int nw = gridDim.x * 4;

    float w1c[16];
#pragma unroll
    for (int k = 0; k < 16; ++k) w1c[k] = W1c[k * 64 + lane];

    for (int n = wg; n < nNodes; n += nw) {
        int rs = row_start[n];
        int re = row_start[n + 1];
        float q = QT[(size_t)n * 64 + lane];
        float tacc = 0.f;
        int i = rs;
        for (; i + 4 <= re; i += 4) {
            int s0 = sorted_src[i + 0];
            int s1 = sorted_src[i + 1];
            int s2 = sorted_src[i + 2];
            int s3 = sorted_src[i + 3];
            float p0 = P[(size_t)s0 * 64 + lane];
            float p1 = P[(size_t)s1 * 64 + lane];
            float p2 = P[(size_t)s2 * 64 + lane];
            float p3 = P[(size_t)s3 * 64 + lane];
            const float4* e4 = reinterpret_cast<const float4*>(sef + (size_t)i * 16);
            float r0 = 0.f, r1 = 0.f, r2 = 0.f, r3 = 0.f;
#pragma unroll
            for (int k = 0; k < 4; ++k) {
                float4 a = e4[k];
                r0 += a.x * w1c[k*4+0] + a.y * w1c[k*4+1]
                    + a.z * w1c[k*4+2] + a.w * w1c[k*4+3];
            }
#pragma unroll
            for (int k = 0; k < 4; ++k) {
                float4 a = e4[4 + k];
                r1 += a.x * w1c[k*4+0] + a.y * w1c[k*4+1]
                    + a.z * w1c[k*4+2] + a.w * w1c[k*4+3];
            }
#pragma unroll
            for (int k = 0; k < 4; ++k) {
                float4 a = e4[8 + k];
                r2 += a.x * w1c[k*4+0] + a.y * w1c[k*4+1]
                    + a.z * w1c[k*4+2] + a.w * w1c[k*4+3];
            }
#pragma unroll
            for (int k = 0; k < 4; ++k) {
                float4 a = e4[12 + k];
                r3 += a.x * w1c[k*4+0] + a.y * w1c[k*4+1]
                    + a.z * w1c[k*4+2] + a.w * w1c[k*4+3];
            }
            float t0 = p0 + q + r0; t0 = t0 > 0.f ? t0 : 0.f;
            float t1 = p1 + q + r1; t1 = t1 > 0.f ? t1 : 0.f;
            float t2 = p2 + q + r2; t2 = t2 > 0.f ? t2 : 0.f;
            float t3 = p3 + q + r3; t3 = t3 > 0.f ? t3 : 0.f;
            tacc += (t0 + t1) + (t2 + t3);
        }
        for (; i < re; ++i) {
            int s = sorted_src[i];
            float p = P[(size_t)s * 64 + lane];
            const float4* e4 = reinterpret_cast<const float4*>(sef + (size_t)i * 16);
            float r = 0.f;
#pragma unroll
            for (int k = 0; k < 4; ++k) {
                float4 a = e4[k];
                r += a.x * w1c[k*4+0] + a.y * w1c[k*4+1]
                   + a.z * w1c[k*4+2] + a.w * w1c[k*4+3];
            }
            float t = p + q + r;
            t = t > 0.f ? t : 0.f;
            tacc += t;
        }
        QT[(size_t)n * 64 + lane] = tacc;
    }
}

// ---------------------------------------------------------------------------
// GRU kernel with folded stage-2:  x_eff = T@Wci + deg*b2ih.
// ---------------------------------------------------------------------------
__global__ __launch_bounds__(256) void gru_kernel(
    const float* __restrict__ T, float* __restrict__ h,
    const float* __restrict__ Wci, const float* __restrict__ Whh,
    const float* __restrict__ bih, const float* __restrict__ bhh,
    const float* __restrict__ b2ih, const int* __restrict__ row_start, int n)
{
    __shared__ float xh[4][2][8][64];
    int w = threadIdx.x >> 6;
    int lane = threadIdx.x & 63;
    int base = (blockIdx.x * 4 + w) * 8;
    if (base >= n) return;

#pragma unroll
    for (int i = 0; i < 8; ++i) {
        int node = base + i;
        xh[w][0][i][lane] = T[(size_t)node * 64 + lane];
        xh[w][1][i][lane] = h[(size_t)node * 64 + lane];
    }
    asm volatile("s_waitcnt lgkmcnt(0)" ::: "memory");

    float air[8], ahr[8], aiz[8], ahz[8], ain[8], ahn[8];
    float bir = bih[lane], biz = bih[64 + lane], bin = bih[128 + lane];
    float bhr = bhh[lane], bhz = bhh[64 + lane], bhn = bhh[128 + lane];
    float b2r = b2ih[lane], b2z = b2ih[64 + lane], b2n = b2ih[128 + lane];
#pragma unroll
    for (int i = 0; i < 8; ++i) {
        int node = base + i;
        float dg = (float)(row_start[node + 1] - row_start[node]);
        air[i] = bir + dg * b2r; aiz[i] = biz + dg * b2z; ain[i] = bin + dg * b2n;
        ahr[i] = bhr; ahz[i] = bhz; ahn[i] = bhn;
    }
#pragma unroll 2
    for (int k = 0; k < 64; ++k) {
        float wir = Wci[k * 192 + lane];
        float wiz = Wci[k * 192 + 64 + lane];
        float win = Wci[k * 192 + 128 + lane];
        float whr = Whh[k * 192 + lane];
        float whz = Whh[k * 192 + 64 + lane];
        float whn = Whh[k * 192 + 128 + lane];
#pragma unroll
        for (int i = 0; i < 8; ++i) {
            float xv = xh[w][0][i][k];
            float hv = xh[w][1][i][k];
            air[i] += xv * wir; aiz[i] += xv * wiz; ain[i] += xv * win;
            ahr[i] += hv * whr; ahz[i] += hv * whz; ahn[i] += hv * whn;
        }
    }
#pragma unroll
    for (int i = 0; i < 8; ++i) {
        float r = 1.f / (1.f + __expf(-(air[i] + ahr[i])));
        float z = 1.f / (1.f + __expf(-(aiz[i] + ahz[i])));
        float nn = tanhf(ain[i] + r * ahn[i]);
        float hv = xh[w][1][i][lane];
        h[(size_t)(base + i) * 64 + lane] = (1.f - z) * nn + z * hv;
    }
}

// ---------------------------------------------------------------------------
extern "C" void kernel_launch(void* const* d_in, const int* in_sizes, int n_in,
                              void* d_out, int out_size, void* d_ws, size_t ws_size,
                              hipStream_t stream)
{
    const float* nf    = (const float*)d_in[0];
    const int*   ei    = (const int*)  d_in[1];
    const float* ef    = (const float*)d_in[2];
    const float* enc_W = (const float*)d_in[3];
    const float* enc_b = (const float*)d_in[4];
    const float* mW1   = (const float*)d_in[5];
    const float* mb1   = (const float*)d_in[6];
    const float* mW2   = (const float*)d_in[7];
    const float* mb2   = (const float*)d_in[8];
    const float* gWih  = (const float*)d_in[9];
    const float* gWhh  = (const float*)d_in[10];
    const float* gbih  = (const float*)d_in[11];
    const float* gbhh  = (const float*)d_in[12];
    const float* rW1   = (const float*)d_in[13];
    const float* rb1   = (const float*)d_in[14];
    const float* rW2   = (const float*)d_in[15];
    const float* rb2   = (const float*)d_in[16];

    const int N = in_sizes[0] / HIDDIM;   // 100000
    const int E = in_sizes[2] / EDIM;     // 1200000

    // workspace layout
    char* wsB = (char*)d_ws;
    float* h         = (float*)wsB;                 wsB += (size_t)N * 64 * sizeof(float);
    float* P         = (float*)wsB;                 wsB += (size_t)N * 64 * sizeof(float);
    float* QT        = (float*)wsB;                 wsB += (size_t)N * 64 * sizeof(float);
    int*   row_start = (int*)wsB;                   wsB += (size_t)(N + 1) * sizeof(int);
    int*   cursor    = (int*)wsB;                   wsB += (size_t)N * sizeof(int);
    int*   cnt       = (int*)wsB;                   wsB += (size_t)N * sizeof(int);
    int*   partial   = (int*)wsB;                   wsB += (size_t)1024 * sizeof(int);
    int*   s_src     = (int*)wsB;                   wsB += (size_t)E * sizeof(int);
    float* sef       = (float*)wsB;                 wsB += (size_t)E * 16 * sizeof(float);
    float* Wci       = (float*)wsB;                 wsB += (size_t)3 * 64 * 192 * sizeof(float);
    float* b2ih      = (float*)wsB;                 wsB += (size_t)3 * 192 * sizeof(float);

    const int gemmGrid = (N + 255) / 256;
    const int edgeGrid = (E + 255) / 256;
    const int gruGrid  = (N + 31) / 32;
    const int nScanBlk = (N + 255) / 256;  // 391 <= 1024

    // encoder: h = nf @ enc_W + enc_b
    gemm64_kernel<<<gemmGrid, 256, 0, stream>>>(nf, enc_W, enc_b, h, N, 0);

    // CSR build (once per call)
    hipMemsetAsync(cnt, 0, (size_t)N * sizeof(int), stream);
    count_kernel<<<edgeGrid, 256, 0, stream>>>(ei + E, cnt, E);
    partial_kernel<<<nScanBlk, 256, 0, stream>>>(cnt, partial, N);
    scan_partials_kernel<<<1, 1024, 0, stream>>>(partial, row_start, nScanBlk, N, E);
    scan_blocks_kernel<<<nScanBlk, 256, 0, stream>>>(cnt, partial, row_start, cursor, N);
    fill_kernel<<<edgeGrid, 256, 0, stream>>>(ei, ei + E, ef, cursor, s_src, sef, E);

    // folded GRU input weights (once per call)
    combine_kernel<<<3, 192, 0, stream>>>(mW2, mb2, gWih, Wci, b2ih);

    for (int l = 0; l < 3; ++l) {
        const float* W1  = mW1 + (size_t)l * 144 * 64;
        const float* W1c = W1 + 128 * 64;
        pq_kernel<<<gemmGrid, 256, 0, stream>>>(h, W1, mb1 + (size_t)l * 64, P, QT, N);
        edge_agg_kernel<<<2048, 256, 0, stream>>>(P, QT, sef, W1c, s_src,
                                                  row_start, N);
        gru_kernel<<<gruGrid, 256, 0, stream>>>(
            QT, h,
            Wci + (size_t)l * 64 * 192, gWhh + (size_t)l * 64 * 192,
            gbih + (size_t)l * 192,     gbhh + (size_t)l * 192,
            b2ih + (size_t)l * 192,     row_start, N);
    }

    // readout
    gemm64_kernel<<<gemmGrid, 256, 0, stream>>>(h, rW1, rb1, P, N, 1);
    gemm64_kernel<<<gemmGrid, 256, 0, stream>>>(P, rW2, rb2, (float*)d_out, N, 0);
}

// Round 6
// 882.363 us; speedup vs baseline: 15.0467x; 1.4317x over previous
//
#include <hip/hip_runtime.h>
#include <hip/hip_bf16.h>
#include <math.h>

#define HIDDIM 64
#define EDIM 16

typedef _Float16 h16;
typedef __attribute__((ext_vector_type(8))) _Float16 half8v;
typedef __attribute__((ext_vector_type(4))) float f32x4;
typedef unsigned int uint32;

// ---------------------------------------------------------------------------
// Unified MFMA GEMM (fp16 inputs, fp32 accum): C = epi(A @ B + bias)
// block = 256 thr (4 waves), 64 rows; wave w owns rows 16w..16w+15.
// A staged fp32->fp16 into LDS (row pad +8 -> benign conflicts).
// B pre-packed per-fragment: frag (t,c,lane) = 8 fp16 at Bp[((t*KC+c)*64+lane)*8],
// col = t*16+(lane&15), k = c*32+(lane>>4)*8+i.
// EPI: 0 = store f32 (RELU opt); 1 = pq (P,Q fp16); 2 = fused GRU update.
// ---------------------------------------------------------------------------
template<int K, int N, int EPI, int RELU>
__global__ __launch_bounds__(256) void mfma_gemm_kernel(
    const float* __restrict__ A0, const float* __restrict__ A1,
    const h16* __restrict__ Bp, const float* __restrict__ bias,
    float* __restrict__ outf, h16* __restrict__ outP,
    h16* __restrict__ outQ, float* __restrict__ hbuf,
    const int* __restrict__ row_start, const float* __restrict__ b2ih, int M)
{
    constexpr int KP = K + 8;
    constexpr int NT = N / 16;
    constexpr int KC = K / 32;
    constexpr int R8 = K / 8;
    __shared__ __align__(16) h16 Asub[64 * KP];

    const int mbase = blockIdx.x * 64;
    const int tid = threadIdx.x;
    const int wid = tid >> 6, lane = tid & 63;

    // ---- stage A (fp32 -> fp16) ----
    constexpr int ITERS = 64 * R8 / 256;
#pragma unroll
    for (int it = 0; it < ITERS; ++it) {
        int e8 = tid + it * 256;
        int row = e8 / R8;
        int col = (e8 - row * R8) * 8;
        int grow = mbase + row;
        float v[8];
        if (grow < M) {
            const float* sp;
            if (EPI == 2) {  // A = [T | h]
                sp = (col < 64) ? (A0 + (size_t)grow * 64 + col)
                                : (A1 + (size_t)grow * 64 + (col - 64));
            } else {
                sp = A0 + (size_t)grow * K + col;
            }
            f32x4 a = *(const f32x4*)sp;
            f32x4 b = *(const f32x4*)(sp + 4);
            v[0] = a.x; v[1] = a.y; v[2] = a.z; v[3] = a.w;
            v[4] = b.x; v[5] = b.y; v[6] = b.z; v[7] = b.w;
        } else {
#pragma unroll
            for (int i = 0; i < 8; ++i) v[i] = 0.f;
        }
        half8v hv;
#pragma unroll
        for (int i = 0; i < 8; ++i) hv[i] = (h16)v[i];
        *(half8v*)&Asub[row * KP + col] = hv;
    }
    __syncthreads();

    // ---- MFMA ----
    const int colb = lane & 15;
    f32x4 acc[NT];
#pragma unroll
    for (int t = 0; t < NT; ++t) {
        float bv = bias ? bias[t * 16 + colb] : 0.f;
        acc[t].x = bv; acc[t].y = bv; acc[t].z = bv; acc[t].w = bv;
    }
    const int aoff = (wid * 16 + colb) * KP + (lane >> 4) * 8;
    const half8v* Bv = (const half8v*)Bp;
#pragma unroll
    for (int c = 0; c < KC; ++c) {
        half8v af = *(const half8v*)&Asub[aoff + c * 32];
#pragma unroll
        for (int t = 0; t < NT; ++t) {
            half8v bf = Bv[(t * KC + c) * 64 + lane];
            acc[t] = __builtin_amdgcn_mfma_f32_16x16x32_f16(af, bf, acc[t], 0, 0, 0);
        }
    }

    // ---- epilogue ----  D: col = t*16 + (lane&15), row = (lane>>4)*4 + r
    if (EPI == 0) {
#pragma unroll
        for (int r = 0; r < 4; ++r) {
            int row = mbase + wid * 16 + (lane >> 4) * 4 + r;
            if (row < M) {
#pragma unroll
                for (int t = 0; t < NT; ++t) {
                    float vv = acc[t][r];
                    if (RELU) vv = vv > 0.f ? vv : 0.f;
                    outf[(size_t)row * N + t * 16 + colb] = vv;
                }
            }
        }
    } else if (EPI == 1) {
#pragma unroll
        for (int r = 0; r < 4; ++r) {
            int row = mbase + wid * 16 + (lane >> 4) * 4 + r;
            if (row < M) {
#pragma unroll
                for (int t = 0; t < NT; ++t) {
                    h16 us = (h16)acc[t][r];
                    int col = t * 16 + colb;
                    if (t < 4) outP[(size_t)row * 64 + col] = us;
                    else       outQ[(size_t)row * 64 + (col - 64)] = us;
                }
            }
        }
    } else {
        float b2r[4], b2z[4], b2n[4];
#pragma unroll
        for (int j4 = 0; j4 < 4; ++j4) {
            int j = j4 * 16 + colb;
            b2r[j4] = b2ih[j];
            b2z[j4] = b2ih[64 + j];
            b2n[j4] = b2ih[128 + j];
        }
#pragma unroll
        for (int r = 0; r < 4; ++r) {
            int row = mbase + wid * 16 + (lane >> 4) * 4 + r;
            if (row < M) {
                float deg = (float)(row_start[row + 1] - row_start[row]);
#pragma unroll
                for (int j4 = 0; j4 < 4; ++j4) {
                    float rv = acc[j4][r] + deg * b2r[j4];
                    rv = 1.f / (1.f + __expf(-rv));
                    float zv = acc[4 + j4][r] + deg * b2z[j4];
                    zv = 1.f / (1.f + __expf(-zv));
                    float gin = acc[8 + j4][r] + deg * b2n[j4];
                    float ghn = acc[12 + j4][r];
                    float nv = tanhf(gin + rv * ghn);
                    size_t off = (size_t)row * 64 + j4 * 16 + colb;
                    float hold = hbuf[off];
                    hbuf[off] = (1.f - zv) * nv + zv * hold;
                }
            }
        }
    }
}

// ---------------------------------------------------------------------------
// Weight packing kernels (once per call; tiny)
// ---------------------------------------------------------------------------
__global__ __launch_bounds__(256) void pack_plain_kernel(
    const float* __restrict__ B, h16* __restrict__ Bp, int Kd, int Nd)
{
    int idx = blockIdx.x * 256 + threadIdx.x;
    int KC = Kd >> 5;
    int total = (Nd >> 4) * KC * 64;
    if (idx >= total) return;
    int lane = idx & 63, fc = idx >> 6;
    int t = fc / KC, c = fc - t * KC;
    int col = t * 16 + (lane & 15);
    int k0 = c * 32 + (lane >> 4) * 8;
    half8v us;
#pragma unroll
    for (int i = 0; i < 8; ++i) us[i] = (h16)B[(size_t)(k0 + i) * Nd + col];
    *(half8v*)(Bp + (size_t)idx * 8) = us;
}

// pq: B[k][n] = n<64 ? W1a[k][n] : W1b[k][n-64]   (K=64, N=128)
__global__ __launch_bounds__(256) void pack_pq_kernel(
    const float* __restrict__ W1, h16* __restrict__ Bp)
{
    int idx = blockIdx.x * 256 + threadIdx.x;
    if (idx >= 1024) return;
    int lane = idx & 63, fc = idx >> 6;
    int t = fc >> 1, c = fc & 1;
    int n = t * 16 + (lane & 15);
    int k0 = c * 32 + (lane >> 4) * 8;
    half8v us;
#pragma unroll
    for (int i = 0; i < 8; ++i) {
        int k = k0 + i;
        float v = (n < 64) ? W1[(size_t)k * 64 + n]
                           : W1[(size_t)(64 + k) * 64 + (n - 64)];
        us[i] = (h16)v;
    }
    *(half8v*)(Bp + (size_t)idx * 8) = us;
}

// gru: A=[T|h], B [128x256]: n<128: [Wci;Whh]; 128-191: [Wci_n;0]; 192-255: [0;Whh_n]
__global__ __launch_bounds__(256) void pack_gru_kernel(
    const float* __restrict__ Wci, const float* __restrict__ Whh,
    h16* __restrict__ Bp)
{
    int idx = blockIdx.x * 256 + threadIdx.x;
    if (idx >= 4096) return;
    int lane = idx & 63, fc = idx >> 6;
    int t = fc >> 2, c = fc & 3;
    int n = t * 16 + (lane & 15);
    int k0 = c * 32 + (lane >> 4) * 8;
    half8v us;
#pragma unroll
    for (int i = 0; i < 8; ++i) {
        int k = k0 + i;
        float v;
        if (n < 128)      v = (k < 64) ? Wci[(size_t)k * 192 + n]
                                       : Whh[(size_t)(k - 64) * 192 + n];
        else if (n < 192) v = (k < 64) ? Wci[(size_t)k * 192 + n] : 0.f;
        else              v = (k >= 64) ? Whh[(size_t)(k - 64) * 192 + (n - 64)] : 0.f;
        us[i] = (h16)v;
    }
    *(half8v*)(Bp + (size_t)idx * 8) = us;
}

__global__ void bias_pq_kernel(const float* __restrict__ b1, float* __restrict__ out)
{
    int i = threadIdx.x;  // 128
    out[i] = (i < 64) ? 0.f : b1[i - 64];
}

__global__ void bias_gru_kernel(const float* __restrict__ bih,
                                const float* __restrict__ bhh,
                                float* __restrict__ out)
{
    int i = threadIdx.x;  // 256
    float v;
    if (i < 128)      v = bih[i] + bhh[i];
    else if (i < 192) v = bih[i];
    else              v = bhh[i - 64];
    out[i] = v;
}

// ---------------------------------------------------------------------------
// CSR build: count -> 3-stage scan -> fill (+ef permute to fp16)
// ---------------------------------------------------------------------------
__global__ __launch_bounds__(256) void count_kernel(
    const int* __restrict__ dst, int* __restrict__ cnt, int nE)
{
    int e = blockIdx.x * 256 + threadIdx.x;
    if (e >= nE) return;
    atomicAdd(&cnt[dst[e]], 1);
}

__global__ __launch_bounds__(256) void partial_kernel(
    const int* __restrict__ cnt, int* __restrict__ partial, int nNodes)
{
    __shared__ int lds[256];
    int i = blockIdx.x * 256 + threadIdx.x;
    int v = (i < nNodes) ? cnt[i] : 0;
    lds[threadIdx.x] = v;
    __syncthreads();
#pragma unroll
    for (int off = 128; off > 0; off >>= 1) {
        if (threadIdx.x < off) lds[threadIdx.x] += lds[threadIdx.x + off];
        __syncthreads();
    }
    if (threadIdx.x == 0) partial[blockIdx.x] = lds[0];
}

__global__ __launch_bounds__(1024) void scan_partials_kernel(
    int* __restrict__ partial, int* __restrict__ row_start, int nb,
    int nNodes, int nE)
{
    __shared__ int lds[1024];
    int tid = threadIdx.x;
    int v = (tid < nb) ? partial[tid] : 0;
    lds[tid] = v;
    __syncthreads();
    for (int off = 1; off < 1024; off <<= 1) {
        int t = (tid >= off) ? lds[tid - off] : 0;
        __syncthreads();
        lds[tid] += t;
        __syncthreads();
    }
    if (tid < nb) partial[tid] = lds[tid] - v;
    if (tid == 0) row_start[nNodes] = nE;
}

__global__ __launch_bounds__(256) void scan_blocks_kernel(
    const int* __restrict__ cnt, const int* __restrict__ partial,
    int* __restrict__ row_start, int* __restrict__ cursor, int nNodes)
{
    __shared__ int lds[256];
    int i = blockIdx.x * 256 + threadIdx.x;
    int v = (i < nNodes) ? cnt[i] : 0;
    lds[threadIdx.x] = v;
    __syncthreads();
    for (int off = 1; off < 256; off <<= 1) {
        int t = (threadIdx.x >= off) ? lds[threadIdx.x - off] : 0;
        __syncthreads();
        lds[threadIdx.x] += t;
        __syncthreads();
    }
    if (i < nNodes) {
        int excl = partial[blockIdx.x] + lds[threadIdx.x] - v;
        row_start[i] = excl;
        cursor[i] = excl;
    }
}

__global__ __launch_bounds__(256) void fill_kernel(
    const int* __restrict__ src, const int* __restrict__ dst,
    const float* __restrict__ ef, int* __restrict__ cursor,
    int* __restrict__ ss, h16* __restrict__ sefh, int nE)
{
    int e = blockIdx.x * 256 + threadIdx.x;
    if (e >= nE) return;
    int d = dst[e];
    int p = atomicAdd(&cursor[d], 1);
    ss[p] = src[e];
    const float4* er = reinterpret_cast<const float4*>(ef + (size_t)e * 16);
    float4 a0 = er[0], a1 = er[1], a2 = er[2], a3 = er[3];
    half8v u0, u1;
    u0[0]=(h16)a0.x; u0[1]=(h16)a0.y; u0[2]=(h16)a0.z; u0[3]=(h16)a0.w;
    u0[4]=(h16)a1.x; u0[5]=(h16)a1.y; u0[6]=(h16)a1.z; u0[7]=(h16)a1.w;
    u1[0]=(h16)a2.x; u1[1]=(h16)a2.y; u1[2]=(h16)a2.z; u1[3]=(h16)a2.w;
    u1[4]=(h16)a3.x; u1[5]=(h16)a3.y; u1[6]=(h16)a3.z; u1[7]=(h16)a3.w;
    half8v* sr = reinterpret_cast<half8v*>(sefh + (size_t)p * 16);
    sr[0] = u0; sr[1] = u1;
}

// ---------------------------------------------------------------------------
// Combine: Wci[l] = W2[l] @ Wih[l]  [64x192], b2ih[l] = b2[l] @ Wih[l] [192].
// ---------------------------------------------------------------------------
__global__ void combine_kernel(
    const float* __restrict__ mW2, const float* __restrict__ mb2,
    const float* __restrict__ gWih, float* __restrict__ Wci,
    float* __restrict__ b2ih)
{
    int l = blockIdx.x;
    int g = threadIdx.x;
    const float* W2  = mW2  + (size_t)l * 64 * 64;
    const float* Wih = gWih + (size_t)l * 64 * 192;
    const float* b2  = mb2  + (size_t)l * 64;
    float acc[64];
#pragma unroll
    for (int k = 0; k < 64; ++k) acc[k] = 0.f;
    float bacc = 0.f;
#pragma unroll 1
    for (int j = 0; j < 64; ++j) {
        float w = Wih[j * 192 + g];
        bacc += b2[j] * w;
#pragma unroll
        for (int k = 0; k < 64; ++k) acc[k] += W2[k * 64 + j] * w;
    }
    float* o = Wci + (size_t)l * 64 * 192;
#pragma unroll
    for (int k = 0; k < 64; ++k) o[k * 192 + g] = acc[k];
    b2ih[l * 192 + g] = bacc;
}

// ---------------------------------------------------------------------------
// Edge aggregation (fp16 inputs, fp32 accumulate, zero atomics, 4-way ILP):
//   T[n] = sum_e relu(P[src[e]] + Q[n] + sef[p]@W1c)
// ---------------------------------------------------------------------------
__device__ __forceinline__ float edot(const half8v& A, const half8v& B,
                                      const float w[16])
{
    float r = 0.f;
#pragma unroll
    for (int k = 0; k < 8; ++k) r += (float)A[k] * w[k];
#pragma unroll
    for (int k = 0; k < 8; ++k) r += (float)B[k] * w[8 + k];
    return r;
}

__global__ __launch_bounds__(256) void edge_agg_kernel(
    const h16* __restrict__ Pb, const h16* __restrict__ Qb,
    float* __restrict__ T, const h16* __restrict__ sefh,
    const float* __restrict__ W1c, const int* __restrict__ sorted_src,
    const int* __restrict__ row_start, int nNodes)
{
    int wg = blockIdx.x * 4 + (threadIdx.x >> 6);
    wg = __builtin_amdgcn_readfirstlane(wg);
    int lane = threadIdx.x & 63;
    int nw = gridDim.x * 4;

    float w1c[16];
#pragma unroll
    for (int k = 0; k < 16; ++k) w1c[k] = W1c[k * 64 + lane];

    for (int n = wg; n < nNodes; n += nw) {
        int rs = row_start[n];
        int re = row_start[n + 1];
        float q = (float)Qb[(size_t)n * 64 + lane];
        float tacc = 0.f;
        int i = rs;
        for (; i + 4 <= re; i += 4) {
            int s0 = sorted_src[i + 0];
            int s1 = sorted_src[i + 1];
            int s2 = sorted_src[i + 2];
            int s3 = sorted_src[i + 3];
            float p0 = (float)Pb[(size_t)s0 * 64 + lane];
            float p1 = (float)Pb[(size_t)s1 * 64 + lane];
            float p2 = (float)Pb[(size_t)s2 * 64 + lane];
            float p3 = (float)Pb[(size_t)s3 * 64 + lane];
            const half8v* e8 = reinterpret_cast<const half8v*>(sefh + (size_t)i * 16);
            half8v c0 = e8[0], c1 = e8[1], c2 = e8[2], c3 = e8[3];
            half8v c4 = e8[4], c5 = e8[5], c6 = e8[6], c7 = e8[7];
            float r0 = edot(c0, c1, w1c);
            float r1 = edot(c2, c3, w1c);
            float r2 = edot(c4, c5, w1c);
            float r3 = edot(c6, c7, w1c);
            float t0 = p0 + q + r0; t0 = t0 > 0.f ? t0 : 0.f;
            float t1 = p1 + q + r1; t1 = t1 > 0.f ? t1 : 0.f;
            float t2 = p2 + q + r2; t2 = t2 > 0.f ? t2 : 0.f;
            float t3 = p3 + q + r3; t3 = t3 > 0.f ? t3 : 0.f;
            tacc += (t0 + t1) + (t2 + t3);
        }
        for (; i < re; ++i) {
            int s = sorted_src[i];
            float p = (float)Pb[(size_t)s * 64 + lane];
            const half8v* e8 = reinterpret_cast<const half8v*>(sefh + (size_t)i * 16);
            half8v c0 = e8[0], c1 = e8[1];
            float r = edot(c0, c1, w1c);
            float t = p + q + r;
            t = t > 0.f ? t : 0.f;
            tacc += t;
        }
        T[(size_t)n * 64 + lane] = tacc;
    }
}

// ---------------------------------------------------------------------------
extern "C" void kernel_launch(void* const* d_in, const int* in_sizes, int n_in,
                              void* d_out, int out_size, void* d_ws, size_t ws_size,
                              hipStream_t stream)
{
    const float* nf    = (const float*)d_in[0];
    const int*   ei    = (const int*)  d_in[1];
    const float* ef    = (const float*)d_in[2];
    const float* enc_W = (const float*)d_in[3];
    const float* enc_b = (const float*)d_in[4];
    const float* mW1   = (const float*)d_in[5];
    const float* mb1   = (const float*)d_in[6];
    const float* mW2   = (const float*)d_in[7];
    const float* mb2   = (const float*)d_in[8];
    const float* gWih  = (const float*)d_in[9];
    const float* gWhh  = (const float*)d_in[10];
    const float* gbih  = (const float*)d_in[11];
    const float* gbhh  = (const float*)d_in[12];
    const float* rW1   = (const float*)d_in[13];
    const float* rb1   = (const float*)d_in[14];
    const float* rW2   = (const float*)d_in[15];
    const float* rb2   = (const float*)d_in[16];

    const int N = in_sizes[0] / HIDDIM;   // 100000
    const int E = in_sizes[2] / EDIM;     // 1200000

    // workspace layout (256B-aligned slices)
    char* wsB = (char*)d_ws;
    auto alloc = [&](size_t bytes) {
        char* p = wsB;
        wsB += (bytes + 255) & ~(size_t)255;
        return p;
    };
    float* h          = (float*)alloc((size_t)N * 64 * 4);
    float* T          = (float*)alloc((size_t)N * 64 * 4);
    float* Rt         = (float*)alloc((size_t)N * 64 * 4);
    h16*  Pb          = (h16*)alloc((size_t)N * 64 * 2);
    h16*  Qb          = (h16*)alloc((size_t)N * 64 * 2);
    int*   row_start  = (int*)alloc((size_t)(N + 1) * 4);
    int*   cursor     = (int*)alloc((size_t)N * 4);
    int*   cnt        = (int*)alloc((size_t)N * 4);
    int*   partial    = (int*)alloc(1024 * 4);
    int*   s_src      = (int*)alloc((size_t)E * 4);
    h16*  sefh        = (h16*)alloc((size_t)E * 16 * 2);
    float* Wci        = (float*)alloc(3 * 64 * 192 * 4);
    float* b2ih       = (float*)alloc(3 * 192 * 4);
    h16*  encP        = (h16*)alloc(512 * 8 * 2);
    h16*  pqP         = (h16*)alloc(3 * 1024 * 8 * 2);
    h16*  gruP        = (h16*)alloc(3 * 4096 * 8 * 2);
    h16*  ro1P        = (h16*)alloc(512 * 8 * 2);
    h16*  ro2P        = (h16*)alloc(512 * 8 * 2);
    float* bias128    = (float*)alloc(3 * 128 * 4);
    float* bias256    = (float*)alloc(3 * 256 * 4);

    const int gemmGrid = (N + 63) / 64;     // 1563
    const int edgeGrid = (E + 255) / 256;
    const int nScanBlk = (N + 255) / 256;   // 391

    // ---- CSR build ----
    hipMemsetAsync(cnt, 0, (size_t)N * 4, stream);
    count_kernel<<<edgeGrid, 256, 0, stream>>>(ei + E, cnt, E);
    partial_kernel<<<nScanBlk, 256, 0, stream>>>(cnt, partial, N);
    scan_partials_kernel<<<1, 1024, 0, stream>>>(partial, row_start, nScanBlk, N, E);
    scan_blocks_kernel<<<nScanBlk, 256, 0, stream>>>(cnt, partial, row_start, cursor, N);
    fill_kernel<<<edgeGrid, 256, 0, stream>>>(ei, ei + E, ef, cursor, s_src, sefh, E);

    // ---- weight prep ----
    combine_kernel<<<3, 192, 0, stream>>>(mW2, mb2, gWih, Wci, b2ih);
    pack_plain_kernel<<<2, 256, 0, stream>>>(enc_W, encP, 64, 64);
    pack_plain_kernel<<<2, 256, 0, stream>>>(rW1, ro1P, 64, 64);
    pack_plain_kernel<<<2, 256, 0, stream>>>(rW2, ro2P, 64, 64);
    for (int l = 0; l < 3; ++l) {
        pack_pq_kernel<<<4, 256, 0, stream>>>(mW1 + (size_t)l * 144 * 64,
                                              pqP + (size_t)l * 1024 * 8);
        pack_gru_kernel<<<16, 256, 0, stream>>>(Wci + (size_t)l * 64 * 192,
                                                gWhh + (size_t)l * 64 * 192,
                                                gruP + (size_t)l * 4096 * 8);
        bias_pq_kernel<<<1, 128, 0, stream>>>(mb1 + (size_t)l * 64,
                                              bias128 + (size_t)l * 128);
        bias_gru_kernel<<<1, 256, 0, stream>>>(gbih + (size_t)l * 192,
                                               gbhh + (size_t)l * 192,
                                               bias256 + (size_t)l * 256);
    }

    // ---- encoder: h = nf @ enc_W + enc_b ----
    mfma_gemm_kernel<64, 64, 0, 0><<<gemmGrid, 256, 0, stream>>>(
        nf, nullptr, encP, enc_b, h, nullptr, nullptr, nullptr, nullptr, nullptr, N);

    // ---- layers ----
    for (int l = 0; l < 3; ++l) {
        mfma_gemm_kernel<64, 128, 1, 0><<<gemmGrid, 256, 0, stream>>>(
            h, nullptr, pqP + (size_t)l * 1024 * 8, bias128 + (size_t)l * 128,
            nullptr, Pb, Qb, nullptr, nullptr, nullptr, N);
        edge_agg_kernel<<<2048, 256, 0, stream>>>(
            Pb, Qb, T, sefh, mW1 + (size_t)l * 144 * 64 + 128 * 64,
            s_src, row_start, N);
        mfma_gemm_kernel<128, 256, 2, 0><<<gemmGrid, 256, 0, stream>>>(
            T, h, gruP + (size_t)l * 4096 * 8, bias256 + (size_t)l * 256,
            nullptr, nullptr, nullptr, h, row_start, b2ih + (size_t)l * 192, N);
    }

    // ---- readout ----
    mfma_gemm_kernel<64, 64, 0, 1><<<gemmGrid, 256, 0, stream>>>(
        h, nullptr, ro1P, rb1, Rt, nullptr, nullptr, nullptr, nullptr, nullptr, N);
    mfma_gemm_kernel<64, 64, 0, 0><<<gemmGrid, 256, 0, stream>>>(
        Rt, nullptr, ro2P, rb2, (float*)d_out, nullptr, nullptr, nullptr,
        nullptr, nullptr, N);
}

// Round 10
// 824.613 us; speedup vs baseline: 16.1004x; 1.0700x over previous
//
#include <hip/hip_runtime.h>
#include <hip/hip_bf16.h>
#include <math.h>

#define HIDDIM 64
#define EDIM 16

typedef _Float16 h16;
typedef __attribute__((ext_vector_type(8))) _Float16 half8v;
typedef __attribute__((ext_vector_type(2))) _Float16 half2v;
typedef __attribute__((ext_vector_type(4))) float f32x4;
typedef unsigned int uint32;

#if defined(__has_builtin)
#if __has_builtin(__builtin_amdgcn_fdot2)
#define HAS_FDOT2 1
#endif
#endif

// ---------------------------------------------------------------------------
// Unified MFMA GEMM (fp16 inputs, fp32 accum): C = epi(A @ B + bias)
// block = 256 thr (4 waves), 64 rows; wave w owns rows 16w..16w+15.
// A staged into LDS (fp16 direct copy, or fp32->fp16 cvt when AF32).
// B pre-packed per-fragment: frag (t,c,lane) = 8 fp16 at Bp[((t*KC+c)*64+lane)*8],
// col = t*16+(lane&15), k = c*32+(lane>>4)*8+i.
// EPI: 0 = store f32 (RELU opt); 1 = store fp16 (RELU opt);
//      2 = pq split (P,Q fp16); 3 = fused GRU update (fp16 h in-place).
// ---------------------------------------------------------------------------
template<int K, int N, int EPI, int RELU, int AF32>
__global__ __launch_bounds__(256) void mfma_gemm_kernel(
    const float* __restrict__ A0f, const h16* __restrict__ A0h,
    const h16* __restrict__ A1h, const h16* __restrict__ Bp,
    const float* __restrict__ bias, float* __restrict__ outf,
    h16* __restrict__ outh, h16* __restrict__ outQ, h16* __restrict__ hbuf,
    const int* __restrict__ row_start, const float* __restrict__ b2ih, int M)
{
    constexpr int KP = K + 8;
    constexpr int NT = N / 16;
    constexpr int KC = K / 32;
    __shared__ __align__(16) h16 Asub[64 * KP];

    const int mbase = blockIdx.x * 64;
    const int tid = threadIdx.x;
    const int wid = tid >> 6, lane = tid & 63;

    // ---- stage A into LDS ----
    constexpr int C8 = K / 8;               // 8-half chunks per row
    constexpr int ITERS = 64 * C8 / 256;
#pragma unroll
    for (int it = 0; it < ITERS; ++it) {
        int idx = tid + it * 256;
        int row = idx / C8;
        int col = (idx - row * C8) * 8;
        int grow = mbase + row;
        half8v hv;
        if (grow < M) {
            if (AF32) {
                const float* sp = A0f + (size_t)grow * K + col;
                f32x4 a = *(const f32x4*)sp;
                f32x4 b = *(const f32x4*)(sp + 4);
                hv[0]=(h16)a.x; hv[1]=(h16)a.y; hv[2]=(h16)a.z; hv[3]=(h16)a.w;
                hv[4]=(h16)b.x; hv[5]=(h16)b.y; hv[6]=(h16)b.z; hv[7]=(h16)b.w;
            } else {
                const h16* sp;
                if (EPI == 3) {  // A = [T | h]
                    sp = (col < 64) ? (A0h + (size_t)grow * 64 + col)
                                    : (A1h + (size_t)grow * 64 + (col - 64));
                } else {
                    sp = A0h + (size_t)grow * K + col;
                }
                hv = *(const half8v*)sp;
            }
        } else {
#pragma unroll
            for (int i = 0; i < 8; ++i) hv[i] = (h16)0.f;
        }
        *(half8v*)&Asub[row * KP + col] = hv;
    }
    __syncthreads();

    // ---- MFMA ----
    const int colb = lane & 15;
    f32x4 acc[NT];
#pragma unroll
    for (int t = 0; t < NT; ++t) {
        float bv = bias ? bias[t * 16 + colb] : 0.f;
        acc[t].x = bv; acc[t].y = bv; acc[t].z = bv; acc[t].w = bv;
    }
    const int aoff = (wid * 16 + colb) * KP + (lane >> 4) * 8;
    const half8v* Bv = (const half8v*)Bp;
#pragma unroll
    for (int c = 0; c < KC; ++c) {
        half8v af = *(const half8v*)&Asub[aoff + c * 32];
#pragma unroll
        for (int t = 0; t < NT; ++t) {
            half8v bf = Bv[(t * KC + c) * 64 + lane];
            acc[t] = __builtin_amdgcn_mfma_f32_16x16x32_f16(af, bf, acc[t], 0, 0, 0);
        }
    }

    // ---- epilogue ----  D: col = t*16 + (lane&15), row = (lane>>4)*4 + r
    if (EPI == 0) {
#pragma unroll
        for (int r = 0; r < 4; ++r) {
            int row = mbase + wid * 16 + (lane >> 4) * 4 + r;
            if (row < M) {
#pragma unroll
                for (int t = 0; t < NT; ++t) {
                    float vv = acc[t][r];
                    if (RELU) vv = vv > 0.f ? vv : 0.f;
                    outf[(size_t)row * N + t * 16 + colb] = vv;
                }
            }
        }
    } else if (EPI == 1) {
#pragma unroll
        for (int r = 0; r < 4; ++r) {
            int row = mbase + wid * 16 + (lane >> 4) * 4 + r;
            if (row < M) {
#pragma unroll
                for (int t = 0; t < NT; ++t) {
                    float vv = acc[t][r];
                    if (RELU) vv = vv > 0.f ? vv : 0.f;
                    outh[(size_t)row * N + t * 16 + colb] = (h16)vv;
                }
            }
        }
    } else if (EPI == 2) {
#pragma unroll
        for (int r = 0; r < 4; ++r) {
            int row = mbase + wid * 16 + (lane >> 4) * 4 + r;
            if (row < M) {
#pragma unroll
                for (int t = 0; t < NT; ++t) {
                    h16 us = (h16)acc[t][r];
                    int col = t * 16 + colb;
                    if (t < 4) outh[(size_t)row * 64 + col] = us;
                    else       outQ[(size_t)row * 64 + (col - 64)] = us;
                }
            }
        }
    } else {
        float b2r[4], b2z[4], b2n[4];
#pragma unroll
        for (int j4 = 0; j4 < 4; ++j4) {
            int j = j4 * 16 + colb;
            b2r[j4] = b2ih[j];
            b2z[j4] = b2ih[64 + j];
            b2n[j4] = b2ih[128 + j];
        }
#pragma unroll
        for (int r = 0; r < 4; ++r) {
            int row = mbase + wid * 16 + (lane >> 4) * 4 + r;
            if (row < M) {
                float deg = (float)(row_start[row + 1] - row_start[row]);
#pragma unroll
                for (int j4 = 0; j4 < 4; ++j4) {
                    float rv = acc[j4][r] + deg * b2r[j4];
                    rv = 1.f / (1.f + __expf(-rv));
                    float zv = acc[4 + j4][r] + deg * b2z[j4];
                    zv = 1.f / (1.f + __expf(-zv));
                    float gin = acc[8 + j4][r] + deg * b2n[j4];
                    float ghn = acc[12 + j4][r];
                    float nv = tanhf(gin + rv * ghn);
                    size_t off = (size_t)row * 64 + j4 * 16 + colb;
                    float hold = (float)hbuf[off];
                    hbuf[off] = (h16)((1.f - zv) * nv + zv * hold);
                }
            }
        }
    }
}

// ---------------------------------------------------------------------------
// Weight packing kernels (once per call; tiny)
// ---------------------------------------------------------------------------
__global__ __launch_bounds__(256) void pack_plain_kernel(
    const float* __restrict__ B, h16* __restrict__ Bp, int Kd, int Nd)
{
    int idx = blockIdx.x * 256 + threadIdx.x;
    int KC = Kd >> 5;
    int total = (Nd >> 4) * KC * 64;
    if (idx >= total) return;
    int lane = idx & 63, fc = idx >> 6;
    int t = fc / KC, c = fc - t * KC;
    int col = t * 16 + (lane & 15);
    int k0 = c * 32 + (lane >> 4) * 8;
    half8v us;
#pragma unroll
    for (int i = 0; i < 8; ++i) us[i] = (h16)B[(size_t)(k0 + i) * Nd + col];
    *(half8v*)(Bp + (size_t)idx * 8) = us;
}

// pq: B[k][n] = n<64 ? W1a[k][n] : W1b[k][n-64]   (K=64, N=128)
__global__ __launch_bounds__(256) void pack_pq_kernel(
    const float* __restrict__ W1, h16* __restrict__ Bp)
{
    int idx = blockIdx.x * 256 + threadIdx.x;
    if (idx >= 1024) return;
    int lane = idx & 63, fc = idx >> 6;
    int t = fc >> 1, c = fc & 1;
    int n = t * 16 + (lane & 15);
    int k0 = c * 32 + (lane >> 4) * 8;
    half8v us;
#pragma unroll
    for (int i = 0; i < 8; ++i) {
        int k = k0 + i;
        float v = (n < 64) ? W1[(size_t)k * 64 + n]
                           : W1[(size_t)(64 + k) * 64 + (n - 64)];
        us[i] = (h16)v;
    }
    *(half8v*)(Bp + (size_t)idx * 8) = us;
}

// gru: A=[T|h], B [128x256]: n<128: [Wci;Whh]; 128-191: [Wci_n;0]; 192-255: [0;Whh_n]
__global__ __launch_bounds__(256) void pack_gru_kernel(
    const float* __restrict__ Wci, const float* __restrict__ Whh,
    h16* __restrict__ Bp)
{
    int idx = blockIdx.x * 256 + threadIdx.x;
    if (idx >= 4096) return;
    int lane = idx & 63, fc = idx >> 6;
    int t = fc >> 2, c = fc & 3;
    int n = t * 16 + (lane & 15);
    int k0 = c * 32 + (lane >> 4) * 8;
    half8v us;
#pragma unroll
    for (int i = 0; i < 8; ++i) {
        int k = k0 + i;
        float v;
        if (n < 128)      v = (k < 64) ? Wci[(size_t)k * 192 + n]
                                       : Whh[(size_t)(k - 64) * 192 + n];
        else if (n < 192) v = (k < 64) ? Wci[(size_t)k * 192 + n] : 0.f;
        else              v = (k >= 64) ? Whh[(size_t)(k - 64) * 192 + (n - 64)] : 0.f;
        us[i] = (h16)v;
    }
    *(half8v*)(Bp + (size_t)idx * 8) = us;
}

// W1c fp32[3][16][64] -> fp16 (same layout)
__global__ __launch_bounds__(256) void pack_w1c_kernel(
    const float* __restrict__ mW1, h16* __restrict__ w1ch)
{
    int idx = blockIdx.x * 256 + threadIdx.x;
    if (idx >= 3 * 1024) return;
    int l = idx >> 10, r = idx & 1023;
    w1ch[idx] = (h16)mW1[(size_t)l * 144 * 64 + 128 * 64 + r];
}

__global__ void bias_pq_kernel(const float* __restrict__ b1, float* __restrict__ out)
{
    int i = threadIdx.x;  // 128
    out[i] = (i < 64) ? 0.f : b1[i - 64];
}

__global__ void bias_gru_kernel(const float* __restrict__ bih,
                                const float* __restrict__ bhh,
                                float* __restrict__ out)
{
    int i = threadIdx.x;  // 256
    float v;
    if (i < 128)      v = bih[i] + bhh[i];
    else if (i < 192) v = bih[i];
    else              v = bhh[i - 64];
    out[i] = v;
}

// ---------------------------------------------------------------------------
// CSR build: count -> 3-stage scan -> fill (+ef permute to fp16)
// ---------------------------------------------------------------------------
__global__ __launch_bounds__(256) void count_kernel(
    const int* __restrict__ dst, int* __restrict__ cnt, int nE)
{
    int e = blockIdx.x * 256 + threadIdx.x;
    if (e >= nE) return;
    atomicAdd(&cnt[dst[e]], 1);
}

__global__ __launch_bounds__(256) void partial_kernel(
    const int* __restrict__ cnt, int* __restrict__ partial, int nNodes)
{
    __shared__ int lds[256];
    int i = blockIdx.x * 256 + threadIdx.x;
    int v = (i < nNodes) ? cnt[i] : 0;
    lds[threadIdx.x] = v;
    __syncthreads();
#pragma unroll
    for (int off = 128; off > 0; off >>= 1) {
        if (threadIdx.x < off) lds[threadIdx.x] += lds[threadIdx.x + off];
        __syncthreads();
    }
    if (threadIdx.x == 0) partial[blockIdx.x] = lds[0];
}

__global__ __launch_bounds__(1024) void scan_partials_kernel(
    int* __restrict__ partial, int* __restrict__ row_start, int nb,
    int nNodes, int nE)
{
    __shared__ int lds[1024];
    int tid = threadIdx.x;
    int v = (tid < nb) ? partial[tid] : 0;
    lds[tid] = v;
    __syncthreads();
    for (int off = 1; off < 1024; off <<= 1) {
        int t = (tid >= off) ? lds[tid - off] : 0;
        __syncthreads();
        lds[tid] += t;
        __syncthreads();
    }
    if (tid < nb) partial[tid] = lds[tid] - v;
    if (tid == 0) row_start[nNodes] = nE;
}

__global__ __launch_bounds__(256) void scan_blocks_kernel(
    const int* __restrict__ cnt, const int* __restrict__ partial,
    int* __restrict__ row_start, int* __restrict__ cursor, int nNodes)
{
    __shared__ int lds[256];
    int i = blockIdx.x * 256 + threadIdx.x;
    int v = (i < nNodes) ? cnt[i] : 0;
    lds[threadIdx.x] = v;
    __syncthreads();
    for (int off = 1; off < 256; off <<= 1) {
        int t = (threadIdx.x >= off) ? lds[threadIdx.x - off] : 0;
        __syncthreads();
        lds[threadIdx.x] += t;
        __syncthreads();
    }
    if (i < nNodes) {
        int excl = partial[blockIdx.x] + lds[threadIdx.x] - v;
        row_start[i] = excl;
        cursor[i] = excl;
    }
}

__global__ __launch_bounds__(256) void fill_kernel(
    const int* __restrict__ src, const int* __restrict__ dst,
    const float* __restrict__ ef, int* __restrict__ cursor,
    int* __restrict__ ss, h16* __restrict__ sefh, int nE)
{
    int e = blockIdx.x * 256 + threadIdx.x;
    if (e >= nE) return;
    int d = dst[e];
    int p = atomicAdd(&cursor[d], 1);
    ss[p] = src[e];
    const float4* er = reinterpret_cast<const float4*>(ef + (size_t)e * 16);
    float4 a0 = er[0], a1 = er[1], a2 = er[2], a3 = er[3];
    half8v u0, u1;
    u0[0]=(h16)a0.x; u0[1]=(h16)a0.y; u0[2]=(h16)a0.z; u0[3]=(h16)a0.w;
    u0[4]=(h16)a1.x; u0[5]=(h16)a1.y; u0[6]=(h16)a1.z; u0[7]=(h16)a1.w;
    u1[0]=(h16)a2.x; u1[1]=(h16)a2.y; u1[2]=(h16)a2.z; u1[3]=(h16)a2.w;
    u1[4]=(h16)a3.x; u1[5]=(h16)a3.y; u1[6]=(h16)a3.z; u1[7]=(h16)a3.w;
    half8v* sr = reinterpret_cast<half8v*>(sefh + (size_t)p * 16);
    sr[0] = u0; sr[1] = u1;
}

// ---------------------------------------------------------------------------
// Combine: Wci[l] = W2[l] @ Wih[l]  [64x192], b2ih[l] = b2[l] @ Wih[l] [192].
// ---------------------------------------------------------------------------
__global__ void combine_kernel(
    const float* __restrict__ mW2, const float* __restrict__ mb2,
    const float* __restrict__ gWih, float* __restrict__ Wci,
    float* __restrict__ b2ih)
{
    int l = blockIdx.x;
    int g = threadIdx.x;
    const float* W2  = mW2  + (size_t)l * 64 * 64;
    const float* Wih = gWih + (size_t)l * 64 * 192;
    const float* b2  = mb2  + (size_t)l * 64;
    float acc[64];
#pragma unroll
    for (int k = 0; k < 64; ++k) acc[k] = 0.f;
    float bacc = 0.f;
#pragma unroll 1
    for (int j = 0; j < 64; ++j) {
        float w = Wih[j * 192 + g];
        bacc += b2[j] * w;
#pragma unroll
        for (int k = 0; k < 64; ++k) acc[k] += W2[k * 64 + j] * w;
    }
    float* o = Wci + (size_t)l * 64 * 192;
#pragma unroll
    for (int k = 0; k < 64; ++k) o[k * 192 + g] = acc[k];
    b2ih[l * 192 + g] = bacc;
}

// ---------------------------------------------------------------------------
// Edge aggregation (fp16, dot2, fp32 accum, zero atomics, 8/4-way ILP):
//   T[n] = sum_e relu(P[src[e]] + Q[n] + sef[p]@W1c)   (T stored fp16)
// ---------------------------------------------------------------------------
__device__ __forceinline__ float edot16(half8v a, half8v b, const half2v w[8],
                                        float seed)
{
    float r = seed;
#if defined(HAS_FDOT2)
    const half2v* ap = (const half2v*)&a;
    const half2v* bp = (const half2v*)&b;
#pragma unroll
    for (int j = 0; j < 4; ++j) r = __builtin_amdgcn_fdot2(ap[j], w[j], r, false);
#pragma unroll
    for (int j = 0; j < 4; ++j) r = __builtin_amdgcn_fdot2(bp[j], w[4 + j], r, false);
#else
#pragma unroll
    for (int k = 0; k < 8; ++k) r += (float)a[k] * (float)w[k >> 1][k & 1];
#pragma unroll
    for (int k = 0; k < 8; ++k) r += (float)b[k] * (float)w[4 + (k >> 1)][k & 1];
#endif
    return r;
}

__global__ __launch_bounds__(256) void edge_agg_kernel(
    const h16* __restrict__ Pb, const h16* __restrict__ Qb,
    h16* __restrict__ T, const h16* __restrict__ sefh,
    const h16* __restrict__ w1ch, const int* __restrict__ sorted_src,
    const int* __restrict__ row_start, int nNodes)
{
    int wg = blockIdx.x * 4 + (threadIdx.x >> 6);
    wg = __builtin_amdgcn_readfirstlane(wg);
    int lane = threadIdx.x & 63;
    int nw = gridDim.x * 4;

    half2v w2[8];
#pragma unroll
    for (int j = 0; j < 8; ++j) {
        half2v p;
        p[0] = w1ch[(2 * j) * 64 + lane];
        p[1] = w1ch[(2 * j + 1) * 64 + lane];
        w2[j] = p;
    }

    for (int n = wg; n < nNodes; n += nw) {
        int rs = row_start[n];
        int re = row_start[n + 1];
        float q = (float)Qb[(size_t)n * 64 + lane];
        float tacc = 0.f;
        int i = rs;
        for (; i + 8 <= re; i += 8) {
            float p[8];
#pragma unroll
            for (int j = 0; j < 8; ++j) {
                int s = sorted_src[i + j];
                p[j] = (float)Pb[(size_t)s * 64 + lane];
            }
            const half8v* e8 = reinterpret_cast<const half8v*>(sefh + (size_t)i * 16);
#pragma unroll
            for (int j = 0; j < 8; ++j) {
                float t = edot16(e8[2 * j], e8[2 * j + 1], w2, p[j] + q);
                t = t > 0.f ? t : 0.f;
                tacc += t;
            }
        }
        for (; i + 4 <= re; i += 4) {
            float p[4];
#pragma unroll
            for (int j = 0; j < 4; ++j) {
                int s = sorted_src[i + j];
                p[j] = (float)Pb[(size_t)s * 64 + lane];
            }
            const half8v* e8 = reinterpret_cast<const half8v*>(sefh + (size_t)i * 16);
#pragma unroll
            for (int j = 0; j < 4; ++j) {
                float t = edot16(e8[2 * j], e8[2 * j + 1], w2, p[j] + q);
                t = t > 0.f ? t : 0.f;
                tacc += t;
            }
        }
        for (; i < re; ++i) {
            int s = sorted_src[i];
            float p = (float)Pb[(size_t)s * 64 + lane];
            const half8v* e8 = reinterpret_cast<const half8v*>(sefh + (size_t)i * 16);
            float t = edot16(e8[0], e8[1], w2, p + q);
            t = t > 0.f ? t : 0.f;
            tacc += t;
        }
        T[(size_t)n * 64 + lane] = (h16)tacc;
    }
}

// ---------------------------------------------------------------------------
extern "C" void kernel_launch(void* const* d_in, const int* in_sizes, int n_in,
                              void* d_out, int out_size, void* d_ws, size_t ws_size,
                              hipStream_t stream)
{
    const float* nf    = (const float*)d_in[0];
    const int*   ei    = (const int*)  d_in[1];
    const float* ef    = (const float*)d_in[2];
    const float* enc_W = (const float*)d_in[3];
    const float* enc_b = (const float*)d_in[4];
    const float* mW1   = (const float*)d_in[5];
    const float* mb1   = (const float*)d_in[6];
    const float* mW2   = (const float*)d_in[7];
    const float* mb2   = (const float*)d_in[8];
    const float* gWih  = (const float*)d_in[9];
    const float* gWhh  = (const float*)d_in[10];
    const float* gbih  = (const float*)d_in[11];
    const float* gbhh  = (const float*)d_in[12];
    const float* rW1   = (const float*)d_in[13];
    const float* rb1   = (const float*)d_in[14];
    const float* rW2   = (const float*)d_in[15];
    const float* rb2   = (const float*)d_in[16];

    const int N = in_sizes[0] / HIDDIM;   // 100000
    const int E = in_sizes[2] / EDIM;     // 1200000

    // workspace layout (256B-aligned slices)
    char* wsB = (char*)d_ws;
    auto alloc = [&](size_t bytes) {
        char* p = wsB;
        wsB += (bytes + 255) & ~(size_t)255;
        return p;
    };
    h16*  h           = (h16*)alloc((size_t)N * 64 * 2);
    h16*  T           = (h16*)alloc((size_t)N * 64 * 2);
    h16*  Rt          = (h16*)alloc((size_t)N * 64 * 2);
    h16*  Pb          = (h16*)alloc((size_t)N * 64 * 2);
    h16*  Qb          = (h16*)alloc((size_t)N * 64 * 2);
    int*   row_start  = (int*)alloc((size_t)(N + 1) * 4);
    int*   cursor     = (int*)alloc((size_t)N * 4);
    int*   cnt        = (int*)alloc((size_t)N * 4);
    int*   partial    = (int*)alloc(1024 * 4);
    int*   s_src      = (int*)alloc((size_t)E * 4);
    h16*  sefh        = (h16*)alloc((size_t)E * 16 * 2);
    float* Wci        = (float*)alloc(3 * 64 * 192 * 4);
    float* b2ih       = (float*)alloc(3 * 192 * 4);
    h16*  encP        = (h16*)alloc(512 * 8 * 2);
    h16*  pqP         = (h16*)alloc(3 * 1024 * 8 * 2);
    h16*  gruP        = (h16*)alloc(3 * 4096 * 8 * 2);
    h16*  ro1P        = (h16*)alloc(512 * 8 * 2);
    h16*  ro2P        = (h16*)alloc(512 * 8 * 2);
    h16*  w1ch        = (h16*)alloc(3 * 1024 * 2);
    float* bias128    = (float*)alloc(3 * 128 * 4);
    float* bias256    = (float*)alloc(3 * 256 * 4);

    const int gemmGrid = (N + 63) / 64;     // 1563
    const int edgeGrid = (E + 255) / 256;
    const int nScanBlk = (N + 255) / 256;   // 391

    // ---- CSR build ----
    hipMemsetAsync(cnt, 0, (size_t)N * 4, stream);
    count_kernel<<<edgeGrid, 256, 0, stream>>>(ei + E, cnt, E);
    partial_kernel<<<nScanBlk, 256, 0, stream>>>(cnt, partial, N);
    scan_partials_kernel<<<1, 1024, 0, stream>>>(partial, row_start, nScanBlk, N, E);
    scan_blocks_kernel<<<nScanBlk, 256, 0, stream>>>(cnt, partial, row_start, cursor, N);
    fill_kernel<<<edgeGrid, 256, 0, stream>>>(ei, ei + E, ef, cursor, s_src, sefh, E);

    // ---- weight prep ----
    combine_kernel<<<3, 192, 0, stream>>>(mW2, mb2, gWih, Wci, b2ih);
    pack_plain_kernel<<<2, 256, 0, stream>>>(enc_W, encP, 64, 64);
    pack_plain_kernel<<<2, 256, 0, stream>>>(rW1, ro1P, 64, 64);
    pack_plain_kernel<<<2, 256, 0, stream>>>(rW2, ro2P, 64, 64);
    pack_w1c_kernel<<<12, 256, 0, stream>>>(mW1, w1ch);
    for (int l = 0; l < 3; ++l) {
        pack_pq_kernel<<<4, 256, 0, stream>>>(mW1 + (size_t)l * 144 * 64,
                                              pqP + (size_t)l * 1024 * 8);
        pack_gru_kernel<<<16, 256, 0, stream>>>(Wci + (size_t)l * 64 * 192,
                                                gWhh + (size_t)l * 64 * 192,
                                                gruP + (size_t)l * 4096 * 8);
        bias_pq_kernel<<<1, 128, 0, stream>>>(mb1 + (size_t)l * 64,
                                              bias128 + (size_t)l * 128);
        bias_gru_kernel<<<1, 256, 0, stream>>>(gbih + (size_t)l * 192,
                                               gbhh + (size_t)l * 192,
                                               bias256 + (size_t)l * 256);
    }

    // ---- encoder: h = nf @ enc_W + enc_b  (fp32 A, fp16 out) ----
    mfma_gemm_kernel<64, 64, 1, 0, 1><<<gemmGrid, 256, 0, stream>>>(
        nf, nullptr, nullptr, encP, enc_b, nullptr, h, nullptr, nullptr,
        nullptr, nullptr, N);

    // ---- layers ----
    for (int l = 0; l < 3; ++l) {
        mfma_gemm_kernel<64, 128, 2, 0, 0><<<gemmGrid, 256, 0, stream>>>(
            nullptr, h, nullptr, pqP + (size_t)l * 1024 * 8,
            bias128 + (size_t)l * 128, nullptr, Pb, Qb, nullptr,
            nullptr, nullptr, N);
        edge_agg_kernel<<<2048, 256, 0, stream>>>(
            Pb, Qb, T, sefh, w1ch + (size_t)l * 1024, s_src, row_start, N);
        mfma_gemm_kernel<128, 256, 3, 0, 0><<<gemmGrid, 256, 0, stream>>>(
            nullptr, T, h, gruP + (size_t)l * 4096 * 8,
            bias256 + (size_t)l * 256, nullptr, nullptr, nullptr, h,
            row_start, b2ih + (size_t)l * 192, N);
    }

    // ---- readout ----
    mfma_gemm_kernel<64, 64, 1, 1, 0><<<gemmGrid, 256, 0, stream>>>(
        nullptr, h, nullptr, ro1P, rb1, nullptr, Rt, nullptr, nullptr,
        nullptr, nullptr, N);
    mfma_gemm_kernel<64, 64, 0, 0, 0><<<gemmGrid, 256, 0, stream>>>(
        nullptr, Rt, nullptr, ro2P, rb2, (float*)d_out, nullptr, nullptr,
        nullptr, nullptr, nullptr, N);
}

// Round 11
// 786.246 us; speedup vs baseline: 16.8861x; 1.0488x over previous
//
#include <hip/hip_runtime.h>
#include <hip/hip_bf16.h>
#include <math.h>

#define HIDDIM 64
#define EDIM 16

typedef _Float16 h16;
typedef __attribute__((ext_vector_type(8))) _Float16 half8v;
typedef __attribute__((ext_vector_type(2))) _Float16 half2v;
typedef __attribute__((ext_vector_type(4))) float f32x4;
typedef unsigned int uint32;

#if defined(__has_builtin)
#if __has_builtin(__builtin_amdgcn_fdot2)
#define HAS_FDOT2 1
#endif
#endif

// ---------------------------------------------------------------------------
// MFMA helpers. A-tile in LDS: [64][KP] h16, row-padded (+8).
// B pre-packed per-fragment: frag (t,c,lane) = 8 fp16 at Bp[((t*KC+c)*64+lane)*8],
// col = t*16+(lane&15), k = c*32+(lane>>4)*8+i.
// C/D frag: col = t*16+(lane&15), row = (lane>>4)*4 + r.
// ---------------------------------------------------------------------------
template<int KP, int KC, int NT>
__device__ __forceinline__ void run_mfma(const h16* Asub, const h16* Bp,
                                         f32x4* acc, int wid, int lane)
{
    const int colb = lane & 15;
    const int aoff = (wid * 16 + colb) * KP + (lane >> 4) * 8;
    const half8v* Bv = (const half8v*)Bp;
#pragma unroll
    for (int c = 0; c < KC; ++c) {
        half8v af = *(const half8v*)&Asub[aoff + c * 32];
#pragma unroll
        for (int t = 0; t < NT; ++t) {
            half8v bf = Bv[(t * KC + c) * 64 + lane];
            acc[t] = __builtin_amdgcn_mfma_f32_16x16x32_f16(af, bf, acc[t], 0, 0, 0);
        }
    }
}

template<int NT>
__device__ __forceinline__ void init_acc(f32x4* acc, const float* bias, int lane)
{
    const int colb = lane & 15;
#pragma unroll
    for (int t = 0; t < NT; ++t) {
        float bv = bias ? bias[t * 16 + colb] : 0.f;
        acc[t].x = bv; acc[t].y = bv; acc[t].z = bv; acc[t].w = bv;
    }
}

// ---------------------------------------------------------------------------
// Fused encoder + pq0: h = nf@encW+encb (fp16 out, global+LDS) ->
//                      P|Q = h @ pqP0 + bias128_0
// ---------------------------------------------------------------------------
__global__ __launch_bounds__(256) void enc_pq_kernel(
    const float* __restrict__ nf, const h16* __restrict__ encP,
    const float* __restrict__ enc_b, const h16* __restrict__ pqP0,
    const float* __restrict__ bias128_0, h16* __restrict__ hout,
    h16* __restrict__ Pb, h16* __restrict__ Qb, int M)
{
    __shared__ __align__(16) h16 Asub[64 * 72];
    __shared__ __align__(16) h16 Htile[64 * 72];
    const int mbase = blockIdx.x * 64;
    const int tid = threadIdx.x;
    const int wid = tid >> 6, lane = tid & 63;
    const int colb = lane & 15;

    // stage nf (fp32 -> fp16): 8 chunks/row, 2 iters
#pragma unroll
    for (int it = 0; it < 2; ++it) {
        int idx = tid + it * 256;
        int row = idx >> 3;
        int col = (idx & 7) * 8;
        int grow = mbase + row;
        half8v hv;
        if (grow < M) {
            const float* sp = nf + (size_t)grow * 64 + col;
            f32x4 a = *(const f32x4*)sp;
            f32x4 b = *(const f32x4*)(sp + 4);
            hv[0]=(h16)a.x; hv[1]=(h16)a.y; hv[2]=(h16)a.z; hv[3]=(h16)a.w;
            hv[4]=(h16)b.x; hv[5]=(h16)b.y; hv[6]=(h16)b.z; hv[7]=(h16)b.w;
        } else {
#pragma unroll
            for (int i = 0; i < 8; ++i) hv[i] = (h16)0.f;
        }
        *(half8v*)&Asub[row * 72 + col] = hv;
    }
    __syncthreads();

    f32x4 acc[4];
    init_acc<4>(acc, enc_b, lane);
    run_mfma<72, 2, 4>(Asub, encP, acc, wid, lane);

    // h -> global + Htile
#pragma unroll
    for (int r = 0; r < 4; ++r) {
        int lrow = wid * 16 + (lane >> 4) * 4 + r;
        int grow = mbase + lrow;
#pragma unroll
        for (int t = 0; t < 4; ++t) {
            h16 v = (h16)acc[t][r];
            Htile[lrow * 72 + t * 16 + colb] = v;
            if (grow < M) hout[(size_t)grow * 64 + t * 16 + colb] = v;
        }
    }
    __syncthreads();

    f32x4 acc2[8];
    init_acc<8>(acc2, bias128_0, lane);
    run_mfma<72, 2, 8>(Htile, pqP0, acc2, wid, lane);

#pragma unroll
    for (int r = 0; r < 4; ++r) {
        int grow = mbase + wid * 16 + (lane >> 4) * 4 + r;
        if (grow < M) {
#pragma unroll
            for (int t = 0; t < 8; ++t) {
                h16 us = (h16)acc2[t][r];
                int col = t * 16 + colb;
                if (t < 4) Pb[(size_t)grow * 64 + col] = us;
                else       Qb[(size_t)grow * 64 + (col - 64)] = us;
            }
        }
    }
}

// ---------------------------------------------------------------------------
// Fused GRU + next-layer pq.
// ---------------------------------------------------------------------------
__global__ __launch_bounds__(256) void gru_pq_kernel(
    const h16* __restrict__ T, h16* __restrict__ h,
    const h16* __restrict__ gruP, const float* __restrict__ bias256,
    const int* __restrict__ row_start, const float* __restrict__ b2ih,
    const h16* __restrict__ pqPn, const float* __restrict__ bias128n,
    h16* __restrict__ Pb, h16* __restrict__ Qb, int M)
{
    __shared__ __align__(16) h16 Asub[64 * 136];
    __shared__ __align__(16) h16 Htile[64 * 72];
    const int mbase = blockIdx.x * 64;
    const int tid = threadIdx.x;
    const int wid = tid >> 6, lane = tid & 63;
    const int colb = lane & 15;

    // stage [T | h]: 16 chunks/row, 4 iters
#pragma unroll
    for (int it = 0; it < 4; ++it) {
        int idx = tid + it * 256;
        int row = idx >> 4;
        int col = (idx & 15) * 8;
        int grow = mbase + row;
        half8v hv;
        if (grow < M) {
            const h16* sp = (col < 64) ? (T + (size_t)grow * 64 + col)
                                       : (h + (size_t)grow * 64 + (col - 64));
            hv = *(const half8v*)sp;
        } else {
#pragma unroll
            for (int i = 0; i < 8; ++i) hv[i] = (h16)0.f;
        }
        *(half8v*)&Asub[row * 136 + col] = hv;
    }
    __syncthreads();

    f32x4 acc[16];
    init_acc<16>(acc, bias256, lane);
    run_mfma<136, 4, 16>(Asub, gruP, acc, wid, lane);

    float b2r[4], b2z[4], b2n[4];
#pragma unroll
    for (int j4 = 0; j4 < 4; ++j4) {
        int j = j4 * 16 + colb;
        b2r[j4] = b2ih[j]; b2z[j4] = b2ih[64 + j]; b2n[j4] = b2ih[128 + j];
    }
#pragma unroll
    for (int r = 0; r < 4; ++r) {
        int lrow = wid * 16 + (lane >> 4) * 4 + r;
        int grow = mbase + lrow;
        float deg = (grow < M) ? (float)(row_start[grow + 1] - row_start[grow]) : 0.f;
#pragma unroll
        for (int j4 = 0; j4 < 4; ++j4) {
            float rv = acc[j4][r] + deg * b2r[j4];
            rv = 1.f / (1.f + __expf(-rv));
            float zv = acc[4 + j4][r] + deg * b2z[j4];
            zv = 1.f / (1.f + __expf(-zv));
            float gin = acc[8 + j4][r] + deg * b2n[j4];
            float ghn = acc[12 + j4][r];
            float nv = tanhf(gin + rv * ghn);
            float hold = (float)Asub[lrow * 136 + 64 + j4 * 16 + colb];
            h16 hv = (h16)((1.f - zv) * nv + zv * hold);
            Htile[lrow * 72 + j4 * 16 + colb] = hv;
            if (grow < M) h[(size_t)grow * 64 + j4 * 16 + colb] = hv;
        }
    }
    __syncthreads();

    f32x4 acc2[8];
    init_acc<8>(acc2, bias128n, lane);
    run_mfma<72, 2, 8>(Htile, pqPn, acc2, wid, lane);

#pragma unroll
    for (int r = 0; r < 4; ++r) {
        int grow = mbase + wid * 16 + (lane >> 4) * 4 + r;
        if (grow < M) {
#pragma unroll
            for (int t = 0; t < 8; ++t) {
                h16 us = (h16)acc2[t][r];
                int col = t * 16 + colb;
                if (t < 4) Pb[(size_t)grow * 64 + col] = us;
                else       Qb[(size_t)grow * 64 + (col - 64)] = us;
            }
        }
    }
}

// ---------------------------------------------------------------------------
// Fused last GRU + readout (h stays in LDS; out f32).
// ---------------------------------------------------------------------------
__global__ __launch_bounds__(256) void gru_ro_kernel(
    const h16* __restrict__ T, const h16* __restrict__ h,
    const h16* __restrict__ gruP, const float* __restrict__ bias256,
    const int* __restrict__ row_start, const float* __restrict__ b2ih,
    const h16* __restrict__ ro1P, const float* __restrict__ rb1,
    const h16* __restrict__ ro2P, const float* __restrict__ rb2,
    float* __restrict__ out, int M)
{
    __shared__ __align__(16) h16 Asub[64 * 136];
    __shared__ __align__(16) h16 Htile[64 * 72];
    const int mbase = blockIdx.x * 64;
    const int tid = threadIdx.x;
    const int wid = tid >> 6, lane = tid & 63;
    const int colb = lane & 15;

#pragma unroll
    for (int it = 0; it < 4; ++it) {
        int idx = tid + it * 256;
        int row = idx >> 4;
        int col = (idx & 15) * 8;
        int grow = mbase + row;
        half8v hv;
        if (grow < M) {
            const h16* sp = (col < 64) ? (T + (size_t)grow * 64 + col)
                                       : (h + (size_t)grow * 64 + (col - 64));
            hv = *(const half8v*)sp;
        } else {
#pragma unroll
            for (int i = 0; i < 8; ++i) hv[i] = (h16)0.f;
        }
        *(half8v*)&Asub[row * 136 + col] = hv;
    }
    __syncthreads();

    f32x4 acc[16];
    init_acc<16>(acc, bias256, lane);
    run_mfma<136, 4, 16>(Asub, gruP, acc, wid, lane);

    float b2r[4], b2z[4], b2n[4];
#pragma unroll
    for (int j4 = 0; j4 < 4; ++j4) {
        int j = j4 * 16 + colb;
        b2r[j4] = b2ih[j]; b2z[j4] = b2ih[64 + j]; b2n[j4] = b2ih[128 + j];
    }
#pragma unroll
    for (int r = 0; r < 4; ++r) {
        int lrow = wid * 16 + (lane >> 4) * 4 + r;
        int grow = mbase + lrow;
        float deg = (grow < M) ? (float)(row_start[grow + 1] - row_start[grow]) : 0.f;
#pragma unroll
        for (int j4 = 0; j4 < 4; ++j4) {
            float rv = acc[j4][r] + deg * b2r[j4];
            rv = 1.f / (1.f + __expf(-rv));
            float zv = acc[4 + j4][r] + deg * b2z[j4];
            zv = 1.f / (1.f + __expf(-zv));
            float gin = acc[8 + j4][r] + deg * b2n[j4];
            float ghn = acc[12 + j4][r];
            float nv = tanhf(gin + rv * ghn);
            float hold = (float)Asub[lrow * 136 + 64 + j4 * 16 + colb];
            Htile[lrow * 72 + j4 * 16 + colb] = (h16)((1.f - zv) * nv + zv * hold);
        }
    }
    __syncthreads();        // all Asub reads done -> Asub reusable

    f32x4 acc2[4];
    init_acc<4>(acc2, rb1, lane);
    run_mfma<72, 2, 4>(Htile, ro1P, acc2, wid, lane);

    // relu -> Rtile (reuse Asub, pitch 72)
#pragma unroll
    for (int r = 0; r < 4; ++r) {
        int lrow = wid * 16 + (lane >> 4) * 4 + r;
#pragma unroll
        for (int t = 0; t < 4; ++t) {
            float v = acc2[t][r];
            v = v > 0.f ? v : 0.f;
            Asub[lrow * 72 + t * 16 + colb] = (h16)v;
        }
    }
    __syncthreads();

    f32x4 acc3[4];
    init_acc<4>(acc3, rb2, lane);
    run_mfma<72, 2, 4>(Asub, ro2P, acc3, wid, lane);

#pragma unroll
    for (int r = 0; r < 4; ++r) {
        int grow = mbase + wid * 16 + (lane >> 4) * 4 + r;
        if (grow < M) {
#pragma unroll
            for (int t = 0; t < 4; ++t)
                out[(size_t)grow * 64 + t * 16 + colb] = acc3[t][r];
        }
    }
}

// ---------------------------------------------------------------------------
// Weight packing (consolidated; once per call)
// ---------------------------------------------------------------------------
__global__ __launch_bounds__(256) void pack_plain3_kernel(
    const float* __restrict__ encW, const float* __restrict__ rW1,
    const float* __restrict__ rW2, h16* __restrict__ encP,
    h16* __restrict__ ro1P, h16* __restrict__ ro2P)
{
    int idx = blockIdx.x * 256 + threadIdx.x;
    if (idx >= 1536) return;
    int w = idx >> 9, u = idx & 511;
    const float* B = (w == 0) ? encW : (w == 1) ? rW1 : rW2;
    h16* Bp = (w == 0) ? encP : (w == 1) ? ro1P : ro2P;
    int lane = u & 63, fc = u >> 6;
    int t = fc >> 1, c = fc & 1;
    int col = t * 16 + (lane & 15);
    int k0 = c * 32 + (lane >> 4) * 8;
    half8v us;
#pragma unroll
    for (int i = 0; i < 8; ++i) us[i] = (h16)B[(size_t)(k0 + i) * 64 + col];
    *(half8v*)(Bp + (size_t)u * 8) = us;
}

__global__ __launch_bounds__(256) void pack_pq_all_kernel(
    const float* __restrict__ mW1, h16* __restrict__ pqP)
{
    int idx = blockIdx.x * 256 + threadIdx.x;
    if (idx >= 3 * 1024) return;
    int l = idx >> 10, u = idx & 1023;
    const float* W1 = mW1 + (size_t)l * 144 * 64;
    int lane = u & 63, fc = u >> 6;
    int t = fc >> 1, c = fc & 1;
    int n = t * 16 + (lane & 15);
    int k0 = c * 32 + (lane >> 4) * 8;
    half8v us;
#pragma unroll
    for (int i = 0; i < 8; ++i) {
        int k = k0 + i;
        float v = (n < 64) ? W1[(size_t)k * 64 + n]
                           : W1[(size_t)(64 + k) * 64 + (n - 64)];
        us[i] = (h16)v;
    }
    *(half8v*)(pqP + (size_t)idx * 8) = us;
}

__global__ __launch_bounds__(256) void pack_gru_all_kernel(
    const float* __restrict__ Wci, const float* __restrict__ gWhh,
    h16* __restrict__ gruP)
{
    int idx = blockIdx.x * 256 + threadIdx.x;
    if (idx >= 3 * 4096) return;
    int l = idx >> 12, u = idx & 4095;
    const float* Wc = Wci + (size_t)l * 64 * 192;
    const float* Wh = gWhh + (size_t)l * 64 * 192;
    int lane = u & 63, fc = u >> 6;
    int t = fc >> 2, c = fc & 3;
    int n = t * 16 + (lane & 15);
    int k0 = c * 32 + (lane >> 4) * 8;
    half8v us;
#pragma unroll
    for (int i = 0; i < 8; ++i) {
        int k = k0 + i;
        float v;
        if (n < 128)      v = (k < 64) ? Wc[(size_t)k * 192 + n]
                                       : Wh[(size_t)(k - 64) * 192 + n];
        else if (n < 192) v = (k < 64) ? Wc[(size_t)k * 192 + n] : 0.f;
        else              v = (k >= 64) ? Wh[(size_t)(k - 64) * 192 + (n - 64)] : 0.f;
        us[i] = (h16)v;
    }
    *(half8v*)(gruP + (size_t)idx * 8) = us;
}

__global__ __launch_bounds__(256) void pack_w1c_kernel(
    const float* __restrict__ mW1, h16* __restrict__ w1ch)
{
    int idx = blockIdx.x * 256 + threadIdx.x;
    if (idx >= 3 * 1024) return;
    int l = idx >> 10, r = idx & 1023;
    w1ch[idx] = (h16)mW1[(size_t)l * 144 * 64 + 128 * 64 + r];
}

__global__ void bias_all_kernel(
    const float* __restrict__ mb1, const float* __restrict__ gbih,
    const float* __restrict__ gbhh, float* __restrict__ bias128,
    float* __restrict__ bias256)
{
    int l = blockIdx.x, i = threadIdx.x;
    if (i < 128)
        bias128[l * 128 + i] = (i < 64) ? 0.f : mb1[l * 64 + i - 64];
    const float* bih = gbih + l * 192;
    const float* bhh = gbhh + l * 192;
    float v;
    if (i < 128)      v = bih[i] + bhh[i];
    else if (i < 192) v = bih[i];
    else              v = bhh[i - 64];
    bias256[l * 256 + i] = v;
}

// ---------------------------------------------------------------------------
// CSR build
// ---------------------------------------------------------------------------
__global__ __launch_bounds__(256) void count_kernel(
    const int* __restrict__ dst, int* __restrict__ cnt, int nE)
{
    int e = blockIdx.x * 256 + threadIdx.x;
    if (e >= nE) return;
    atomicAdd(&cnt[dst[e]], 1);
}

__global__ __launch_bounds__(256) void partial_kernel(
    const int* __restrict__ cnt, int* __restrict__ partial, int nNodes)
{
    __shared__ int lds[256];
    int i = blockIdx.x * 256 + threadIdx.x;
    int v = (i < nNodes) ? cnt[i] : 0;
    lds[threadIdx.x] = v;
    __syncthreads();
#pragma unroll
    for (int off = 128; off > 0; off >>= 1) {
        if (threadIdx.x < off) lds[threadIdx.x] += lds[threadIdx.x + off];
        __syncthreads();
    }
    if (threadIdx.x == 0) partial[blockIdx.x] = lds[0];
}

__global__ __launch_bounds__(1024) void scan_partials_kernel(
    int* __restrict__ partial, int* __restrict__ row_start, int nb,
    int nNodes, int nE)
{
    __shared__ int lds[1024];
    int tid = threadIdx.x;
    int v = (tid < nb) ? partial[tid] : 0;
    lds[tid] = v;
    __syncthreads();
    for (int off = 1; off < 1024; off <<= 1) {
        int t = (tid >= off) ? lds[tid - off] : 0;
        __syncthreads();
        lds[tid] += t;
        __syncthreads();
    }
    if (tid < nb) partial[tid] = lds[tid] - v;
    if (tid == 0) row_start[nNodes] = nE;
}

__global__ __launch_bounds__(256) void scan_blocks_kernel(
    const int* __restrict__ cnt, const int* __restrict__ partial,
    int* __restrict__ row_start, int* __restrict__ cursor, int nNodes)
{
    __shared__ int lds[256];
    int i = blockIdx.x * 256 + threadIdx.x;
    int v = (i < nNodes) ? cnt[i] : 0;
    lds[threadIdx.x] = v;
    __syncthreads();
    for (int off = 1; off < 256; off <<= 1) {
        int t = (threadIdx.x >= off) ? lds[threadIdx.x - off] : 0;
        __syncthreads();
        lds[threadIdx.x] += t;
        __syncthreads();
    }
    if (i < nNodes) {
        int excl = partial[blockIdx.x] + lds[threadIdx.x] - v;
        row_start[i] = excl;
        cursor[i] = excl;
    }
}

__global__ __launch_bounds__(256) void fill_kernel(
    const int* __restrict__ src, const int* __restrict__ dst,
    const float* __restrict__ ef, int* __restrict__ cursor,
    int* __restrict__ ss, h16* __restrict__ sefh, int nE)
{
    int e = blockIdx.x * 256 + threadIdx.x;
    if (e >= nE) return;
    int d = dst[e];
    int p = atomicAdd(&cursor[d], 1);
    ss[p] = src[e];
    const float4* er = reinterpret_cast<const float4*>(ef + (size_t)e * 16);
    float4 a0 = er[0], a1 = er[1], a2 = er[2], a3 = er[3];
    half8v u0, u1;
    u0[0]=(h16)a0.x; u0[1]=(h16)a0.y; u0[2]=(h16)a0.z; u0[3]=(h16)a0.w;
    u0[4]=(h16)a1.x; u0[5]=(h16)a1.y; u0[6]=(h16)a1.z; u0[7]=(h16)a1.w;
    u1[0]=(h16)a2.x; u1[1]=(h16)a2.y; u1[2]=(h16)a2.z; u1[3]=(h16)a2.w;
    u1[4]=(h16)a3.x; u1[5]=(h16)a3.y; u1[6]=(h16)a3.z; u1[7]=(h16)a3.w;
    half8v* sr = reinterpret_cast<half8v*>(sefh + (size_t)p * 16);
    sr[0] = u0; sr[1] = u1;
}

// ---------------------------------------------------------------------------
__global__ void combine_kernel(
    const float* __restrict__ mW2, const float* __restrict__ mb2,
    const float* __restrict__ gWih, float* __restrict__ Wci,
    float* __restrict__ b2ih)
{
    int l = blockIdx.x;
    int g = threadIdx.x;
    const float* W2  = mW2  + (size_t)l * 64 * 64;
    const float* Wih = gWih + (size_t)l * 64 * 192;
    const float* b2  = mb2  + (size_t)l * 64;
    float acc[64];
#pragma unroll
    for (int k = 0; k < 64; ++k) acc[k] = 0.f;
    float bacc = 0.f;
#pragma unroll 1
    for (int j = 0; j < 64; ++j) {
        float w = Wih[j * 192 + g];
        bacc += b2[j] * w;
#pragma unroll
        for (int k = 0; k < 64; ++k) acc[k] += W2[k * 64 + j] * w;
    }
    float* o = Wci + (size_t)l * 64 * 192;
#pragma unroll
    for (int k = 0; k < 64; ++k) o[k * 192 + g] = acc[k];
    b2ih[l * 192 + g] = bacc;
}

// ---------------------------------------------------------------------------
// Edge aggregation (unchanged from round 10)
// ---------------------------------------------------------------------------
__device__ __forceinline__ float edot16(half8v a, half8v b, const half2v w[8],
                                        float seed)
{
    float r = seed;
#if defined(HAS_FDOT2)
    const half2v* ap = (const half2v*)&a;
    const half2v* bp = (const half2v*)&b;
#pragma unroll
    for (int j = 0; j < 4; ++j) r = __builtin_amdgcn_fdot2(ap[j], w[j], r, false);
#pragma unroll
    for (int j = 0; j < 4; ++j) r = __builtin_amdgcn_fdot2(bp[j], w[4 + j], r, false);
#else
#pragma unroll
    for (int k = 0; k < 8; ++k) r += (float)a[k] * (float)w[k >> 1][k & 1];
#pragma unroll
    for (int k = 0; k < 8; ++k) r += (float)b[k] * (float)w[4 + (k >> 1)][k & 1];
#endif
    return r;
}

__global__ __launch_bounds__(256) void edge_agg_kernel(
    const h16* __restrict__ Pb, const h16* __restrict__ Qb,
    h16* __restrict__ T, const h16* __restrict__ sefh,
    const h16* __restrict__ w1ch, const int* __restrict__ sorted_src,
    const int* __restrict__ row_start, int nNodes)
{
    int wg = blockIdx.x * 4 + (threadIdx.x >> 6);
    wg = __builtin_amdgcn_readfirstlane(wg);
    int lane = threadIdx.x & 63;
    int nw = gridDim.x * 4;

    half2v w2[8];
#pragma unroll
    for (int j = 0; j < 8; ++j) {
        half2v p;
        p[0] = w1ch[(2 * j) * 64 + lane];
        p[1] = w1ch[(2 * j + 1) * 64 + lane];
        w2[j] = p;
    }

    for (int n = wg; n < nNodes; n += nw) {
        int rs = row_start[n];
        int re = row_start[n + 1];
        float q = (float)Qb[(size_t)n * 64 + lane];
        float tacc = 0.f;
        int i = rs;
        for (; i + 8 <= re; i += 8) {
            float p[8];
#pragma unroll
            for (int j = 0; j < 8; ++j) {
                int s = sorted_src[i + j];
                p[j] = (float)Pb[(size_t)s * 64 + lane];
            }
            const half8v* e8 = reinterpret_cast<const half8v*>(sefh + (size_t)i * 16);
#pragma unroll
            for (int j = 0; j < 8; ++j) {
                float t = edot16(e8[2 * j], e8[2 * j + 1], w2, p[j] + q);
                t = t > 0.f ? t : 0.f;
                tacc += t;
            }
        }
        for (; i + 4 <= re; i += 4) {
            float p[4];
#pragma unroll
            for (int j = 0; j < 4; ++j) {
                int s = sorted_src[i + j];
                p[j] = (float)Pb[(size_t)s * 64 + lane];
            }
            const half8v* e8 = reinterpret_cast<const half8v*>(sefh + (size_t)i * 16);
#pragma unroll
            for (int j = 0; j < 4; ++j) {
                float t = edot16(e8[2 * j], e8[2 * j + 1], w2, p[j] + q);
                t = t > 0.f ? t : 0.f;
                tacc += t;
            }
        }
        for (; i < re; ++i) {
            int s = sorted_src[i];
            float p = (float)Pb[(size_t)s * 64 + lane];
            const half8v* e8 = reinterpret_cast<const half8v*>(sefh + (size_t)i * 16);
            float t = edot16(e8[0], e8[1], w2, p + q);
            t = t > 0.f ? t : 0.f;
            tacc += t;
        }
        T[(size_t)n * 64 + lane] = (h16)tacc;
    }
}

// ---------------------------------------------------------------------------
extern "C" void kernel_launch(void* const* d_in, const int* in_sizes, int n_in,
                              void* d_out, int out_size, void* d_ws, size_t ws_size,
                              hipStream_t stream)
{
    const float* nf    = (const float*)d_in[0];
    const int*   ei    = (const int*)  d_in[1];
    const float* ef    = (const float*)d_in[2];
    const float* enc_W = (const float*)d_in[3];
    const float* enc_b = (const float*)d_in[4];
    const float* mW1   = (const float*)d_in[5];
    const float* mb1   = (const float*)d_in[6];
    const float* mW2   = (const float*)d_in[7];
    const float* mb2   = (const float*)d_in[8];
    const float* gWih  = (const float*)d_in[9];
    const float* gWhh  = (const float*)d_in[10];
    const float* gbih  = (const float*)d_in[11];
    const float* gbhh  = (const float*)d_in[12];
    const float* rW1   = (const float*)d_in[13];
    const float* rb1   = (const float*)d_in[14];
    const float* rW2   = (const float*)d_in[15];
    const float* rb2   = (const float*)d_in[16];

    const int N = in_sizes[0] / HIDDIM;   // 100000
    const int E = in_sizes[2] / EDIM;     // 1200000

    char* wsB = (char*)d_ws;
    auto alloc = [&](size_t bytes) {
        char* p = wsB;
        wsB += (bytes + 255) & ~(size_t)255;
        return p;
    };
    h16*  h           = (h16*)alloc((size_t)N * 64 * 2);
    h16*  T           = (h16*)alloc((size_t)N * 64 * 2);
    h16*  Pb          = (h16*)alloc((size_t)N * 64 * 2);
    h16*  Qb          = (h16*)alloc((size_t)N * 64 * 2);
    int*   row_start  = (int*)alloc((size_t)(N + 1) * 4);
    int*   cursor     = (int*)alloc((size_t)N * 4);
    int*   cnt        = (int*)alloc((size_t)N * 4);
    int*   partial    = (int*)alloc(1024 * 4);
    int*   s_src      = (int*)alloc((size_t)E * 4);
    h16*  sefh        = (h16*)alloc((size_t)E * 16 * 2);
    float* Wci        = (float*)alloc(3 * 64 * 192 * 4);
    float* b2ih       = (float*)alloc(3 * 192 * 4);
    h16*  encP        = (h16*)alloc(512 * 8 * 2);
    h16*  pqP         = (h16*)alloc(3 * 1024 * 8 * 2);
    h16*  gruP        = (h16*)alloc(3 * 4096 * 8 * 2);
    h16*  ro1P        = (h16*)alloc(512 * 8 * 2);
    h16*  ro2P        = (h16*)alloc(512 * 8 * 2);
    h16*  w1ch        = (h16*)alloc(3 * 1024 * 2);
    float* bias128    = (float*)alloc(3 * 128 * 4);
    float* bias256    = (float*)alloc(3 * 256 * 4);

    const int gemmGrid = (N + 63) / 64;     // 1563
    const int edgeGrid = (E + 255) / 256;
    const int nScanBlk = (N + 255) / 256;   // 391

    // ---- CSR build ----
    hipMemsetAsync(cnt, 0, (size_t)N * 4, stream);
    count_kernel<<<edgeGrid, 256, 0, stream>>>(ei + E, cnt, E);
    partial_kernel<<<nScanBlk, 256, 0, stream>>>(cnt, partial, N);
    scan_partials_kernel<<<1, 1024, 0, stream>>>(partial, row_start, nScanBlk, N, E);
    scan_blocks_kernel<<<nScanBlk, 256, 0, stream>>>(cnt, partial, row_start, cursor, N);
    fill_kernel<<<edgeGrid, 256, 0, stream>>>(ei, ei + E, ef, cursor, s_src, sefh, E);

    // ---- weight prep (consolidated: 6 dispatches) ----
    combine_kernel<<<3, 192, 0, stream>>>(mW2, mb2, gWih, Wci, b2ih);
    pack_plain3_kernel<<<6, 256, 0, stream>>>(enc_W, rW1, rW2, encP, ro1P, ro2P);
    pack_pq_all_kernel<<<12, 256, 0, stream>>>(mW1, pqP);
    pack_gru_all_kernel<<<48, 256, 0, stream>>>(Wci, gWhh, gruP);
    pack_w1c_kernel<<<12, 256, 0, stream>>>(mW1, w1ch);
    bias_all_kernel<<<3, 256, 0, stream>>>(mb1, gbih, gbhh, bias128, bias256);

    // ---- fused encoder + pq(layer 0) ----
    enc_pq_kernel<<<gemmGrid, 256, 0, stream>>>(
        nf, encP, enc_b, pqP, bias128, h, Pb, Qb, N);

    // ---- layers 0,1 ----
    for (int l = 0; l < 2; ++l) {
        edge_agg_kernel<<<2048, 256, 0, stream>>>(
            Pb, Qb, T, sefh, w1ch + (size_t)l * 1024, s_src, row_start, N);
        gru_pq_kernel<<<gemmGrid, 256, 0, stream>>>(
            T, h, gruP + (size_t)l * 4096 * 8, bias256 + (size_t)l * 256,
            row_start, b2ih + (size_t)l * 192,
            pqP + (size_t)(l + 1) * 1024 * 8, bias128 + (size_t)(l + 1) * 128,
            Pb, Qb, N);
    }

    // ---- layer 2: edge_agg + fused GRU+readout ----
    edge_agg_kernel<<<2048, 256, 0, stream>>>(
        Pb, Qb, T, sefh, w1ch + (size_t)2 * 1024, s_src, row_start, N);
    gru_ro_kernel<<<gemmGrid, 256, 0, stream>>>(
        T, h, gruP + (size_t)2 * 4096 * 8, bias256 + (size_t)2 * 256,
        row_start, b2ih + (size_t)2 * 192,
        ro1P, rb1, ro2P, rb2, (float*)d_out, N);
}